// Round 6
// baseline (277.026 us; speedup 1.0000x reference)
//
#include <hip/hip_runtime.h>
#include <hip/hip_bf16.h>
#include <math.h>

#define LN_EPS 1e-5f

typedef __attribute__((ext_vector_type(4))) float fx4;
typedef __attribute__((ext_vector_type(8))) short s8v;   // 8 bf16 in 4 VGPRs
typedef __attribute__((ext_vector_type(2))) _Float16 h2v;

__device__ inline unsigned f2bf(float f) {
  unsigned u = __builtin_bit_cast(unsigned, f);
  return (u + 0x7fffu + ((u >> 16) & 1u)) >> 16;
}
__device__ inline unsigned pk2(float a, float b) {
  return f2bf(a) | (f2bf(b) << 16);
}
__device__ inline unsigned short f2h(float f) {
  return __builtin_bit_cast(unsigned short, (_Float16)f);
}

// ---------------------------------------------------------------------------
// prep_adj: one pass over adj f32. Produces:
//   dv[i]  = rsqrt(clip(rowsum(adj_i), 1e-6))
//   Af     = bf16(adj) in MFMA A-fragment layout:
//            uint4 index ((mb64*256 + ktile)*4 + mfq)*64 + lane
//            lane holds row mb64*64+mfq*16+(lane&15), k = ktile*32+(lane>>4)*8..+7
// Block = 16 rows (one mfq slice). 512 blocks.
// NOTE: no nontemporal hints anywhere — nt reads of producer-written buffers
// returned stale data (rounds 3-5, deterministic absmax 2.2).
// ---------------------------------------------------------------------------
__global__ __launch_bounds__(256) void prep_adj(const float* __restrict__ adj,
                                                float* __restrict__ dv,
                                                uint4* __restrict__ Af) {
  const int tid = threadIdx.x;
  const int m0 = blockIdx.x * 16;
  const int r = tid & 15;
  const int cg = tid >> 4;           // 0..15
  const float* src = adj + (long)(m0 + r) * 8192 + cg * 8;
  uint4* wbase = Af + (((long)(blockIdx.x >> 2) * 256) * 4 + (blockIdx.x & 3)) * 64 + (tid & 63);
  const int ksub = tid >> 6;         // which of 4 ktiles per pass

  float s = 0.f;
  #pragma unroll 4
  for (int p = 0; p < 64; ++p) {
    float4 a = *(const float4*)(src + p * 128);
    float4 b = *(const float4*)(src + p * 128 + 4);
    s += (a.x + a.y) + (a.z + a.w) + (b.x + b.y) + (b.z + b.w);
    uint4 o;
    o.x = pk2(a.x, a.y); o.y = pk2(a.z, a.w);
    o.z = pk2(b.x, b.y); o.w = pk2(b.z, b.w);
    wbase[(long)(p * 4 + ksub) * 256] = o;
  }
  // reduce 16 partials per row: lanes {r, r+16, r+32, r+48} in each wave, 4 waves
  s += __shfl_xor(s, 16);
  s += __shfl_xor(s, 32);
  __shared__ float red[4][16];
  if ((tid & 63) < 16) red[tid >> 6][r] = s;
  __syncthreads();
  if (tid < 16) {
    float t = (red[0][tid] + red[1][tid]) + (red[2][tid] + red[3][tid]);
    dv[m0 + tid] = rsqrtf(fmaxf(t, 1e-6f));
  }
}

// ---------------------------------------------------------------------------
// build_xt: X1Ts tile-major pre-swizzled: tile kt (64 k), element offset
//   kt*16384 + n*64 + (g^(n&7))*8   holds x-group g (k = kt*64+g*8..+7), d-scaled.
// ---------------------------------------------------------------------------
__global__ __launch_bounds__(256) void build_xt(const float* __restrict__ x,
                                                const float* __restrict__ dv,
                                                unsigned short* __restrict__ xt) {
  __shared__ float t[64][257];
  const int tid = threadIdx.x;
  const int k0 = blockIdx.x * 64;
  #pragma unroll
  for (int i = 0; i < 16; ++i) {
    int idx = i * 1024 + tid * 4;
    int r = idx >> 8, c = idx & 255;
    float4 v = *(const float4*)(x + (long)(k0 + r) * 256 + c);
    float dd = dv[k0 + r];
    t[r][c] = v.x * dd; t[r][c + 1] = v.y * dd;
    t[r][c + 2] = v.z * dd; t[r][c + 3] = v.w * dd;
  }
  __syncthreads();
  const int n = tid;
  unsigned short* dst = xt + (long)blockIdx.x * 16384 + n * 64;
  #pragma unroll
  for (int gg = 0; gg < 8; ++gg) {
    int q = gg ^ (n & 7);
    uint4 o;
    #pragma unroll
    for (int jj = 0; jj < 4; ++jj) {
      int k = gg * 8 + jj * 2;
      ((unsigned*)&o)[jj] = pk2(t[k][n], t[k + 1][n]);
    }
    *(uint4*)(dst + q * 8) = o;
  }
}

// ---------------------------------------------------------------- W -> bf16
__global__ __launch_bounds__(256) void cvt_w(const float* __restrict__ w,
                                             unsigned short* __restrict__ wb, int n) {
  int i = blockIdx.x * 256 + threadIdx.x;
  if (i * 4 < n) {
    float4 v = *(const float4*)(w + i * 4);
    uint2 o;
    o.x = pk2(v.x, v.y); o.y = pk2(v.z, v.w);
    *(uint2*)(wb + i * 4) = o;
  }
}

// ---------------------------------------------------------------------------
// gemm_big: Cp[by][m][n] = sum_{k chunk} Abf[m][k] * X[n][k]
// A: fragment-layout bf16, direct global->reg (ping-pong). B: global_load_lds,
// double-buffered, swizzled via pre-swizzled source. 512 thr.
// Wave layout 2M x 4N (wave tile 64x64). Output partials stored f16.
// BM=128, BN=256, BK=64.  (round-1 structure — verified passing.)
// splitk=8 gives grid 64x8 = 512 blocks = 2 blocks/CU (64KB LDS x2 fits
// 160KB) so one block's vmcnt/barrier drains are hidden by the other.
// ---------------------------------------------------------------------------
#define BM 128
#define BN 256

__global__ __launch_bounds__(512) void gemm_big(const uint4* __restrict__ Af,
                                                const unsigned short* __restrict__ Bt,
                                                unsigned short* __restrict__ Cp, int kchunk) {
  __shared__ __align__(16) unsigned short Bl[2][BN * 64];
  const int tid = threadIdx.x, lane = tid & 63, w = tid >> 6;
  const int wm = w >> 2, wn = w & 3;          // 2M x 4N
  const long bx = blockIdx.x, by = blockIdx.y;
  const int kbase = (int)by * kchunk;
  const int NT = kchunk >> 6;                 // even (kchunk multiple of 128)

  const uint4* ap = Af + (((bx * 2 + wm) * 256 + (kbase >> 5)) * 4) * 64 + lane;
  const unsigned short* bsrc = Bt + (long)(kbase >> 6) * 16384 + w * 2048 + lane * 8;

  uint4 abA[8], abB[8];
  fx4 acc[4][4] = {};

  auto loadA = [&](int kt, uint4 (&d)[8]) {
    #pragma unroll
    for (int mf = 0; mf < 4; ++mf)
      #pragma unroll
      for (int kk = 0; kk < 2; ++kk)
        d[mf * 2 + kk] = ap[((long)kt * 8 + kk * 4 + mf) * 64];
  };
  auto stageB = [&](int kt, int buf) {
    #pragma unroll
    for (int i = 0; i < 4; ++i)
      __builtin_amdgcn_global_load_lds(
          (const unsigned int*)(bsrc + (long)kt * 16384 + i * 512),
          (unsigned int*)&Bl[buf][(w * 4 + i) * 512], 16, 0, 0);
  };
  auto compute = [&](uint4 (&ab)[8], int buf) {
    #pragma unroll
    for (int kk = 0; kk < 2; ++kk) {
      #pragma unroll
      for (int nf = 0; nf < 4; ++nf) {
        int n = wn * 64 + nf * 16 + (lane & 15);
        int k8 = kk * 4 + (lane >> 4);
        const s8v bf = *(const s8v*)&Bl[buf][n * 64 + ((k8 ^ (n & 7)) << 3)];
        #pragma unroll
        for (int mf = 0; mf < 4; ++mf)
          acc[mf][nf] = __builtin_amdgcn_mfma_f32_16x16x32_bf16(
              *(const s8v*)&ab[mf * 2 + kk], bf, acc[mf][nf], 0, 0, 0);
      }
    }
  };

  stageB(0, 0); loadA(0, abA);
  asm volatile("s_waitcnt vmcnt(8)" ::: "memory");
  __syncthreads();
  for (int kt = 0; kt < NT; kt += 2) {
    stageB(kt + 1, 1); loadA(kt + 1, abB);
    compute(abA, 0);
    asm volatile("s_waitcnt vmcnt(8)" ::: "memory");
    __syncthreads();
    if (kt + 2 < NT) {
      stageB(kt + 2, 0); loadA(kt + 2, abA);
      compute(abB, 1);
      asm volatile("s_waitcnt vmcnt(8)" ::: "memory");
      __syncthreads();
    } else {
      compute(abB, 1);
    }
  }

  unsigned short* outp = Cp + (by * 8192 + bx * BM) * 256;
  #pragma unroll
  for (int mf = 0; mf < 4; ++mf)
    #pragma unroll
    for (int nf = 0; nf < 4; ++nf)
      #pragma unroll
      for (int j = 0; j < 4; ++j) {
        int r = wm * 64 + mf * 16 + (lane >> 4) * 4 + j;
        int cc = wn * 64 + nf * 16 + (lane & 15);
        outp[(long)r * 256 + cc] = f2h(acc[mf][nf][j]);
      }
}

// ---------------------------------------------------------------------------
// epi_kernel: splitK-reduce (f16 partials) + d-scale + (h @ W^T + b) + LN +
// GELU + out. 32-row tiles, 256 blocks, 256 threads (4 waves, wave tile 16x128).
// ---------------------------------------------------------------------------
template <int LAYER2>
__global__ __launch_bounds__(256) void epi_kernel(const unsigned short* __restrict__ Cp, int splitk,
                                                  const float* __restrict__ dv,
                                                  const unsigned short* __restrict__ Wb,
                                                  const float* __restrict__ bias,
                                                  const float* __restrict__ g,
                                                  const float* __restrict__ beta,
                                                  const float* __restrict__ xres,
                                                  unsigned short* __restrict__ xtOut,
                                                  float* __restrict__ out) {
  __shared__ __align__(16) unsigned short hA[32 * 256];
  __shared__ float Zl[32][257];
  __shared__ float redS[4][32], redSS[4][32];
  __shared__ float stats[32][2];
  const int tid = threadIdx.x, lane = tid & 63, w = tid >> 6;
  const int m0 = blockIdx.x * 32;

  // phase 1: split-K reduce (f16 partials) + d-scale -> bf16 LDS (swizzled)
  #pragma unroll
  for (int i = 0; i < 8; ++i) {
    int idx = i * 1024 + tid * 4;
    int r = idx >> 8, c = idx & 255;
    float sx = 0.f, sy = 0.f, sz = 0.f, sw = 0.f;
    for (int sk = 0; sk < splitk; ++sk) {
      uint2 v = *(const uint2*)(Cp + ((long)sk * 8192 + m0 + r) * 256 + c);
      h2v p0 = __builtin_bit_cast(h2v, v.x);
      h2v p1 = __builtin_bit_cast(h2v, v.y);
      sx += (float)p0.x; sy += (float)p0.y;
      sz += (float)p1.x; sw += (float)p1.y;
    }
    float dd = dv[m0 + r];
    uint2 o;
    o.x = pk2(sx * dd, sy * dd); o.y = pk2(sz * dd, sw * dd);
    *(uint2*)&hA[r * 256 + (c ^ ((r & 7) << 3))] = o;
  }
  __syncthreads();

  // phase 2: Z = h @ W^T (wave (wm,wn) = (w>>1, w&1), tile 16x128)
  fx4 acc[8] = {};
  const int row = (w >> 1) * 16 + (lane & 15);
  #pragma unroll
  for (int k0 = 0; k0 < 256; k0 += 32) {
    int kc = k0 + (lane >> 4) * 8;
    s8v a = *(const s8v*)&hA[row * 256 + (kc ^ ((row & 7) << 3))];
    #pragma unroll
    for (int nf = 0; nf < 8; ++nf) {
      int n = (w & 1) * 128 + nf * 16 + (lane & 15);
      s8v b = *(const s8v*)(Wb + (long)n * 256 + kc);
      acc[nf] = __builtin_amdgcn_mfma_f32_16x16x32_bf16(a, b, acc[nf], 0, 0, 0);
    }
  }

  // phase 3: + bias -> Zl
  #pragma unroll
  for (int nf = 0; nf < 8; ++nf)
    #pragma unroll
    for (int j = 0; j < 4; ++j) {
      int r = (w >> 1) * 16 + (lane >> 4) * 4 + j;
      int cc = (w & 1) * 128 + nf * 16 + (lane & 15);
      Zl[r][cc] = acc[nf][j] + bias[cc];
    }
  __syncthreads();

  // phase 4: LN stats (8 threads/row)
  {
    int r = tid & 31, q = tid >> 5;
    float s = 0.f, ss = 0.f;
    #pragma unroll
    for (int c = 0; c < 32; ++c) {
      float v = Zl[r][q * 32 + c];
      s += v; ss += v * v;
    }
    s += __shfl_xor(s, 32); ss += __shfl_xor(ss, 32);
    if (lane < 32) { redS[w][r] = s; redSS[w][r] = ss; }
  }
  __syncthreads();
  if (tid < 32) {
    float s = (redS[0][tid] + redS[1][tid]) + (redS[2][tid] + redS[3][tid]);
    float ss = (redSS[0][tid] + redSS[1][tid]) + (redSS[2][tid] + redSS[3][tid]);
    float mu = s * (1.f / 256.f);
    float var = ss * (1.f / 256.f) - mu * mu;
    stats[tid][0] = mu; stats[tid][1] = rsqrtf(var + LN_EPS);
  }
  __syncthreads();

  // phase 5: LN apply + GELU (+ next-layer d-scale)
  {
    int r = tid & 31, q = tid >> 5;
    float mu = stats[r][0], inv = stats[r][1];
    float dd = LAYER2 ? 1.f : dv[m0 + r];
    #pragma unroll
    for (int c = 0; c < 32; ++c) {
      int cc = q * 32 + c;
      float v = (Zl[r][cc] - mu) * inv * g[cc] + beta[cc];
      float ge = 0.5f * v * (1.f + erff(v * 0.70710678118f));
      Zl[r][cc] = ge * dd;
    }
  }
  __syncthreads();

  // phase 6: output
  if (!LAYER2) {
    // X2Ts tile-major pre-swizzled (same convention as build_xt)
    int n = tid;
    unsigned short* dst = xtOut + ((long)(m0 >> 6)) * 16384 + n * 64;
    int g0 = (m0 & 32) >> 3;   // 0 or 4
    #pragma unroll
    for (int gi = 0; gi < 4; ++gi) {
      int gg = g0 + gi;
      int q = gg ^ (n & 7);
      uint4 o;
      #pragma unroll
      for (int jj = 0; jj < 4; ++jj) {
        int rr = gi * 8 + jj * 2;
        ((unsigned*)&o)[jj] = pk2(Zl[rr][n], Zl[rr + 1][n]);
      }
      *(uint4*)(dst + q * 8) = o;
    }
  } else {
    int c = tid;
    #pragma unroll 8
    for (int r = 0; r < 32; ++r) {
      long idx = (long)(m0 + r) * 256 + c;
      out[idx] = Zl[r][c] + xres[idx];
    }
  }
}

// ---------------------------------------------------------------- launcher
extern "C" void kernel_launch(void* const* d_in, const int* in_sizes, int n_in,
                              void* d_out, int out_size, void* d_ws, size_t ws_size,
                              hipStream_t stream) {
  const float* x   = (const float*)d_in[0];
  const float* adj = (const float*)d_in[1];
  const float* W1  = (const float*)d_in[2];
  const float* b1  = (const float*)d_in[3];
  const float* g1  = (const float*)d_in[4];
  const float* be1 = (const float*)d_in[5];
  const float* W2  = (const float*)d_in[6];
  const float* b2  = (const float*)d_in[7];
  const float* g2  = (const float*)d_in[8];
  const float* be2 = (const float*)d_in[9];
  float* out = (float*)d_out;

  char* ws = (char*)d_ws;
  size_t off = 0;
  uint4* Af = (uint4*)(ws); off += 134217728;                       // 128 MB
  unsigned short* X1T = (unsigned short*)(ws + off); off += 4194304;
  unsigned short* X2T = (unsigned short*)(ws + off); off += 4194304;
  unsigned short* W1b = (unsigned short*)(ws + off); off += 131072;
  unsigned short* W2b = (unsigned short*)(ws + off); off += 131072;
  float* dvec = (float*)(ws + off); off += 32768;
  unsigned short* Cpart = (unsigned short*)(ws + off);

  int splitk = 8;   // 512 gemm blocks = 2 blocks/CU (was 4 -> 1 block/CU)
  while (splitk > 1 && off + (size_t)splitk * 8192 * 256 * 2 > ws_size) splitk >>= 1;
  int kchunk = 8192 / splitk;

  prep_adj<<<512, 256, 0, stream>>>(adj, dvec, Af);
  build_xt<<<128, 256, 0, stream>>>(x, dvec, X1T);
  cvt_w<<<64, 256, 0, stream>>>(W1, W1b, 65536);
  cvt_w<<<64, 256, 0, stream>>>(W2, W2b, 65536);

  gemm_big<<<dim3(64, splitk), 512, 0, stream>>>(Af, X1T, Cpart, kchunk);
  epi_kernel<0><<<256, 256, 0, stream>>>(Cpart, splitk, dvec, W1b, b1, g1, be1,
                                         nullptr, X2T, nullptr);
  gemm_big<<<dim3(64, splitk), 512, 0, stream>>>(Af, X2T, Cpart, kchunk);
  epi_kernel<1><<<256, 256, 0, stream>>>(Cpart, splitk, dvec, W2b, b2, g2, be2,
                                         x, nullptr, out);
}

// Round 7
// 251.955 us; speedup vs baseline: 1.0995x; 1.0995x over previous
//
#include <hip/hip_runtime.h>
#include <hip/hip_bf16.h>
#include <math.h>

#define LN_EPS 1e-5f

typedef __attribute__((ext_vector_type(4))) float fx4;
typedef __attribute__((ext_vector_type(8))) short s8v;   // 8 bf16 in 4 VGPRs
typedef __attribute__((ext_vector_type(2))) _Float16 h2v;

__device__ inline unsigned f2bf(float f) {
  unsigned u = __builtin_bit_cast(unsigned, f);
  return (u + 0x7fffu + ((u >> 16) & 1u)) >> 16;
}
__device__ inline unsigned pk2(float a, float b) {
  return f2bf(a) | (f2bf(b) << 16);
}
__device__ inline unsigned short f2h(float f) {
  return __builtin_bit_cast(unsigned short, (_Float16)f);
}

// ---------------------------------------------------------------------------
// prep_adj: one pass over adj f32. Produces:
//   dv[i]  = rsqrt(clip(rowsum(adj_i), 1e-6))
//   Af     = bf16(adj) in MFMA A-fragment layout:
//            uint4 index ((mb64*256 + ktile)*4 + mfq)*64 + lane
//            lane holds row mb64*64+mfq*16+(lane&15), k = ktile*32+(lane>>4)*8..+7
// Block = 16 rows (one mfq slice). 512 blocks.
// NOTE: no nontemporal hints anywhere — nt reads of producer-written buffers
// returned stale data (rounds 3-5, deterministic absmax 2.2).
// ---------------------------------------------------------------------------
__global__ __launch_bounds__(256) void prep_adj(const float* __restrict__ adj,
                                                float* __restrict__ dv,
                                                uint4* __restrict__ Af) {
  const int tid = threadIdx.x;
  const int m0 = blockIdx.x * 16;
  const int r = tid & 15;
  const int cg = tid >> 4;           // 0..15
  const float* src = adj + (long)(m0 + r) * 8192 + cg * 8;
  uint4* wbase = Af + (((long)(blockIdx.x >> 2) * 256) * 4 + (blockIdx.x & 3)) * 64 + (tid & 63);
  const int ksub = tid >> 6;         // which of 4 ktiles per pass

  float s = 0.f;
  #pragma unroll 4
  for (int p = 0; p < 64; ++p) {
    float4 a = *(const float4*)(src + p * 128);
    float4 b = *(const float4*)(src + p * 128 + 4);
    s += (a.x + a.y) + (a.z + a.w) + (b.x + b.y) + (b.z + b.w);
    uint4 o;
    o.x = pk2(a.x, a.y); o.y = pk2(a.z, a.w);
    o.z = pk2(b.x, b.y); o.w = pk2(b.z, b.w);
    wbase[(long)(p * 4 + ksub) * 256] = o;
  }
  // reduce 16 partials per row: lanes {r, r+16, r+32, r+48} in each wave, 4 waves
  s += __shfl_xor(s, 16);
  s += __shfl_xor(s, 32);
  __shared__ float red[4][16];
  if ((tid & 63) < 16) red[tid >> 6][r] = s;
  __syncthreads();
  if (tid < 16) {
    float t = (red[0][tid] + red[1][tid]) + (red[2][tid] + red[3][tid]);
    dv[m0 + tid] = rsqrtf(fmaxf(t, 1e-6f));
  }
}

// ---------------------------------------------------------------------------
// build_xt: blocks 0..127: X1Ts tile-major pre-swizzled: tile kt (64 k),
//   element offset kt*16384 + n*64 + (g^(n&7))*8 holds x-group g, d-scaled.
// Blocks 128..191: W1 f32->bf16.  Blocks 192..255: W2 f32->bf16.
// (cvt folded in to save two kernel launches; block-uniform branch.)
// ---------------------------------------------------------------------------
__global__ __launch_bounds__(256) void build_xt(const float* __restrict__ x,
                                                const float* __restrict__ dv,
                                                unsigned short* __restrict__ xt,
                                                const float* __restrict__ W1,
                                                unsigned short* __restrict__ W1b,
                                                const float* __restrict__ W2,
                                                unsigned short* __restrict__ W2b) {
  const int tid = threadIdx.x;
  if (blockIdx.x >= 128) {
    const int wi = blockIdx.x >= 192;
    const float* wsrc = wi ? W2 : W1;
    unsigned short* wdst = wi ? W2b : W1b;
    int i = (blockIdx.x - (wi ? 192 : 128)) * 256 + tid;
    float4 v = *(const float4*)(wsrc + i * 4);
    uint2 o;
    o.x = pk2(v.x, v.y); o.y = pk2(v.z, v.w);
    *(uint2*)(wdst + i * 4) = o;
    return;
  }
  __shared__ float t[64][257];
  const int k0 = blockIdx.x * 64;
  #pragma unroll
  for (int i = 0; i < 16; ++i) {
    int idx = i * 1024 + tid * 4;
    int r = idx >> 8, c = idx & 255;
    float4 v = *(const float4*)(x + (long)(k0 + r) * 256 + c);
    float dd = dv[k0 + r];
    t[r][c] = v.x * dd; t[r][c + 1] = v.y * dd;
    t[r][c + 2] = v.z * dd; t[r][c + 3] = v.w * dd;
  }
  __syncthreads();
  const int n = tid;
  unsigned short* dst = xt + (long)blockIdx.x * 16384 + n * 64;
  #pragma unroll
  for (int gg = 0; gg < 8; ++gg) {
    int q = gg ^ (n & 7);
    uint4 o;
    #pragma unroll
    for (int jj = 0; jj < 4; ++jj) {
      int k = gg * 8 + jj * 2;
      ((unsigned*)&o)[jj] = pk2(t[k][n], t[k + 1][n]);
    }
    *(uint4*)(dst + q * 8) = o;
  }
}

// ---------------------------------------------------------------------------
// gemm_big: Cp[by][m][n] = sum_{k chunk} Abf[m][k] * X[n][k]
// A: fragment-layout bf16, direct global->reg (ping-pong). B: global_load_lds,
// double-buffered, swizzled via pre-swizzled source. 512 thr, waves 4x2,
// wave tile 32x128. BM=128, BN=256, BK=64.  (round-0 structure — best known.)
// Output partials stored f16 (halves split-K round-trip; proven r1/r6).
// ---------------------------------------------------------------------------
#define BM 128
#define BN 256

__global__ __launch_bounds__(512) void gemm_big(const uint4* __restrict__ Af,
                                                const unsigned short* __restrict__ Bt,
                                                unsigned short* __restrict__ Cp, int kchunk) {
  __shared__ __align__(16) unsigned short Bl[2][BN * 64];
  const int tid = threadIdx.x, lane = tid & 63, w = tid >> 6;
  const int wm = w >> 1, wn = w & 1;
  const long bx = blockIdx.x, by = blockIdx.y;
  const int kbase = (int)by * kchunk;
  const int NT = kchunk >> 6;

  const uint4* ap = Af + (((bx * 2 + (wm >> 1)) * 256 + (kbase >> 5)) * 4 + (wm & 1) * 2) * 64 + lane;
  const unsigned short* bsrc = Bt + (long)(kbase >> 6) * 16384 + w * 2048 + lane * 8;

  uint4 abA[4], abB[4];
  fx4 acc[2][8] = {};

  auto loadA = [&](int kt, uint4 (&d)[4]) {
    #pragma unroll
    for (int mf = 0; mf < 2; ++mf)
      #pragma unroll
      for (int kk = 0; kk < 2; ++kk)
        d[mf * 2 + kk] = ap[((long)kt * 8 + kk * 4 + mf) * 64];
  };
  auto stageB = [&](int kt, int buf) {
    #pragma unroll
    for (int i = 0; i < 4; ++i)
      __builtin_amdgcn_global_load_lds(
          (const unsigned int*)(bsrc + (long)kt * 16384 + i * 512),
          (unsigned int*)&Bl[buf][(w * 4 + i) * 512], 16, 0, 0);
  };
  auto compute = [&](uint4 (&ab)[4], int buf) {
    #pragma unroll
    for (int kk = 0; kk < 2; ++kk) {
      #pragma unroll
      for (int nf = 0; nf < 8; ++nf) {
        int n = wn * 128 + nf * 16 + (lane & 15);
        int k8 = kk * 4 + (lane >> 4);
        const s8v bf = *(const s8v*)&Bl[buf][n * 64 + ((k8 ^ (n & 7)) << 3)];
        #pragma unroll
        for (int mf = 0; mf < 2; ++mf)
          acc[mf][nf] = __builtin_amdgcn_mfma_f32_16x16x32_bf16(
              *(const s8v*)&ab[mf * 2 + kk], bf, acc[mf][nf], 0, 0, 0);
      }
    }
  };

  loadA(0, abA); stageB(0, 0);
  asm volatile("s_waitcnt vmcnt(0)" ::: "memory");
  __syncthreads();
  for (int kt = 0; kt < NT; kt += 2) {
    if (kt + 1 < NT) { stageB(kt + 1, 1); loadA(kt + 1, abB); }
    compute(abA, 0);
    asm volatile("s_waitcnt vmcnt(0)" ::: "memory");
    __syncthreads();
    if (kt + 2 < NT) { stageB(kt + 2, 0); loadA(kt + 2, abA); }
    if (kt + 1 < NT) {
      compute(abB, 1);
      asm volatile("s_waitcnt vmcnt(0)" ::: "memory");
      __syncthreads();
    }
  }

  unsigned short* outp = Cp + (by * 8192 + bx * BM) * 256;
  #pragma unroll
  for (int mf = 0; mf < 2; ++mf)
    #pragma unroll
    for (int nf = 0; nf < 8; ++nf)
      #pragma unroll
      for (int j = 0; j < 4; ++j) {
        int r = wm * 32 + mf * 16 + (lane >> 4) * 4 + j;
        int cc = wn * 128 + nf * 16 + (lane & 15);
        outp[(long)r * 256 + cc] = f2h(acc[mf][nf][j]);
      }
}

// ---------------------------------------------------------------------------
// epi_kernel: splitK-reduce (f16 partials) + d-scale + (h @ W^T + b) + LN +
// GELU + out. 32-row tiles, 256 blocks, 256 threads (4 waves, wave tile 16x128).
// ---------------------------------------------------------------------------
template <int LAYER2>
__global__ __launch_bounds__(256) void epi_kernel(const unsigned short* __restrict__ Cp, int splitk,
                                                  const float* __restrict__ dv,
                                                  const unsigned short* __restrict__ Wb,
                                                  const float* __restrict__ bias,
                                                  const float* __restrict__ g,
                                                  const float* __restrict__ beta,
                                                  const float* __restrict__ xres,
                                                  unsigned short* __restrict__ xtOut,
                                                  float* __restrict__ out) {
  __shared__ __align__(16) unsigned short hA[32 * 256];
  __shared__ float Zl[32][257];
  __shared__ float redS[4][32], redSS[4][32];
  __shared__ float stats[32][2];
  const int tid = threadIdx.x, lane = tid & 63, w = tid >> 6;
  const int m0 = blockIdx.x * 32;

  // phase 1: split-K reduce (f16 partials) + d-scale -> bf16 LDS (swizzled)
  #pragma unroll
  for (int i = 0; i < 8; ++i) {
    int idx = i * 1024 + tid * 4;
    int r = idx >> 8, c = idx & 255;
    float sx = 0.f, sy = 0.f, sz = 0.f, sw = 0.f;
    for (int sk = 0; sk < splitk; ++sk) {
      uint2 v = *(const uint2*)(Cp + ((long)sk * 8192 + m0 + r) * 256 + c);
      h2v p0 = __builtin_bit_cast(h2v, v.x);
      h2v p1 = __builtin_bit_cast(h2v, v.y);
      sx += (float)p0.x; sy += (float)p0.y;
      sz += (float)p1.x; sw += (float)p1.y;
    }
    float dd = dv[m0 + r];
    uint2 o;
    o.x = pk2(sx * dd, sy * dd); o.y = pk2(sz * dd, sw * dd);
    *(uint2*)&hA[r * 256 + (c ^ ((r & 7) << 3))] = o;
  }
  __syncthreads();

  // phase 2: Z = h @ W^T (wave (wm,wn) = (w>>1, w&1), tile 16x128)
  fx4 acc[8] = {};
  const int row = (w >> 1) * 16 + (lane & 15);
  #pragma unroll
  for (int k0 = 0; k0 < 256; k0 += 32) {
    int kc = k0 + (lane >> 4) * 8;
    s8v a = *(const s8v*)&hA[row * 256 + (kc ^ ((row & 7) << 3))];
    #pragma unroll
    for (int nf = 0; nf < 8; ++nf) {
      int n = (w & 1) * 128 + nf * 16 + (lane & 15);
      s8v b = *(const s8v*)(Wb + (long)n * 256 + kc);
      acc[nf] = __builtin_amdgcn_mfma_f32_16x16x32_bf16(a, b, acc[nf], 0, 0, 0);
    }
  }

  // phase 3: + bias -> Zl
  #pragma unroll
  for (int nf = 0; nf < 8; ++nf)
    #pragma unroll
    for (int j = 0; j < 4; ++j) {
      int r = (w >> 1) * 16 + (lane >> 4) * 4 + j;
      int cc = (w & 1) * 128 + nf * 16 + (lane & 15);
      Zl[r][cc] = acc[nf][j] + bias[cc];
    }
  __syncthreads();

  // phase 4: LN stats (8 threads/row)
  {
    int r = tid & 31, q = tid >> 5;
    float s = 0.f, ss = 0.f;
    #pragma unroll
    for (int c = 0; c < 32; ++c) {
      float v = Zl[r][q * 32 + c];
      s += v; ss += v * v;
    }
    s += __shfl_xor(s, 32); ss += __shfl_xor(ss, 32);
    if (lane < 32) { redS[w][r] = s; redSS[w][r] = ss; }
  }
  __syncthreads();
  if (tid < 32) {
    float s = (redS[0][tid] + redS[1][tid]) + (redS[2][tid] + redS[3][tid]);
    float ss = (redSS[0][tid] + redSS[1][tid]) + (redSS[2][tid] + redSS[3][tid]);
    float mu = s * (1.f / 256.f);
    float var = ss * (1.f / 256.f) - mu * mu;
    stats[tid][0] = mu; stats[tid][1] = rsqrtf(var + LN_EPS);
  }
  __syncthreads();

  // phase 5: LN apply + GELU (+ next-layer d-scale)
  {
    int r = tid & 31, q = tid >> 5;
    float mu = stats[r][0], inv = stats[r][1];
    float dd = LAYER2 ? 1.f : dv[m0 + r];
    #pragma unroll
    for (int c = 0; c < 32; ++c) {
      int cc = q * 32 + c;
      float v = (Zl[r][cc] - mu) * inv * g[cc] + beta[cc];
      float ge = 0.5f * v * (1.f + erff(v * 0.70710678118f));
      Zl[r][cc] = ge * dd;
    }
  }
  __syncthreads();

  // phase 6: output
  if (!LAYER2) {
    // X2Ts tile-major pre-swizzled (same convention as build_xt)
    int n = tid;
    unsigned short* dst = xtOut + ((long)(m0 >> 6)) * 16384 + n * 64;
    int g0 = (m0 & 32) >> 3;   // 0 or 4
    #pragma unroll
    for (int gi = 0; gi < 4; ++gi) {
      int gg = g0 + gi;
      int q = gg ^ (n & 7);
      uint4 o;
      #pragma unroll
      for (int jj = 0; jj < 4; ++jj) {
        int rr = gi * 8 + jj * 2;
        ((unsigned*)&o)[jj] = pk2(Zl[rr][n], Zl[rr + 1][n]);
      }
      *(uint4*)(dst + q * 8) = o;
    }
  } else {
    int c = tid;
    #pragma unroll 8
    for (int r = 0; r < 32; ++r) {
      long idx = (long)(m0 + r) * 256 + c;
      out[idx] = Zl[r][c] + xres[idx];
    }
  }
}

// ---------------------------------------------------------------- launcher
extern "C" void kernel_launch(void* const* d_in, const int* in_sizes, int n_in,
                              void* d_out, int out_size, void* d_ws, size_t ws_size,
                              hipStream_t stream) {
  const float* x   = (const float*)d_in[0];
  const float* adj = (const float*)d_in[1];
  const float* W1  = (const float*)d_in[2];
  const float* b1  = (const float*)d_in[3];
  const float* g1  = (const float*)d_in[4];
  const float* be1 = (const float*)d_in[5];
  const float* W2  = (const float*)d_in[6];
  const float* b2  = (const float*)d_in[7];
  const float* g2  = (const float*)d_in[8];
  const float* be2 = (const float*)d_in[9];
  float* out = (float*)d_out;

  char* ws = (char*)d_ws;
  size_t off = 0;
  uint4* Af = (uint4*)(ws); off += 134217728;                       // 128 MB
  unsigned short* X1T = (unsigned short*)(ws + off); off += 4194304;
  unsigned short* X2T = (unsigned short*)(ws + off); off += 4194304;
  unsigned short* W1b = (unsigned short*)(ws + off); off += 131072;
  unsigned short* W2b = (unsigned short*)(ws + off); off += 131072;
  float* dvec = (float*)(ws + off); off += 32768;
  unsigned short* Cpart = (unsigned short*)(ws + off);

  int splitk = 4;
  while (splitk > 1 && off + (size_t)splitk * 8192 * 256 * 2 > ws_size) splitk >>= 1;
  int kchunk = 8192 / splitk;

  prep_adj<<<512, 256, 0, stream>>>(adj, dvec, Af);
  build_xt<<<256, 256, 0, stream>>>(x, dvec, X1T, W1, W1b, W2, W2b);

  gemm_big<<<dim3(64, splitk), 512, 0, stream>>>(Af, X1T, Cpart, kchunk);
  epi_kernel<0><<<256, 256, 0, stream>>>(Cpart, splitk, dvec, W1b, b1, g1, be1,
                                         nullptr, X2T, nullptr);
  gemm_big<<<dim3(64, splitk), 512, 0, stream>>>(Af, X2T, Cpart, kchunk);
  epi_kernel<1><<<256, 256, 0, stream>>>(Cpart, splitk, dvec, W2b, b2, g2, be2,
                                         x, nullptr, out);
}

// Round 8
// 227.682 us; speedup vs baseline: 1.2167x; 1.1066x over previous
//
#include <hip/hip_runtime.h>
#include <hip/hip_bf16.h>
#include <math.h>

#define LN_EPS 1e-5f

typedef __attribute__((ext_vector_type(4))) float fx4;
typedef __attribute__((ext_vector_type(8))) short s8v;   // 8 bf16 in 4 VGPRs
typedef __attribute__((ext_vector_type(2))) _Float16 h2v;

__device__ inline unsigned f2bf(float f) {
  unsigned u = __builtin_bit_cast(unsigned, f);
  return (u + 0x7fffu + ((u >> 16) & 1u)) >> 16;
}
__device__ inline unsigned pk2(float a, float b) {
  return f2bf(a) | (f2bf(b) << 16);
}
__device__ inline unsigned short f2h(float f) {
  return __builtin_bit_cast(unsigned short, (_Float16)f);
}

// ---------------------------------------------------------------------------
// prep_adj: one pass over adj f32. Produces:
//   dv[i]  = rsqrt(clip(rowsum(adj_i), 1e-6))
//   Af     = bf16(adj) in MFMA A-fragment layout:
//            uint4 index ((mb64*256 + ktile)*4 + mfq)*64 + lane
//            lane holds row mb64*64+mfq*16+(lane&15), k = ktile*32+(lane>>4)*8..+7
// Block = 16 rows (one mfq slice). 512 blocks x 512 threads (8 waves):
// 16 waves/CU (4/SIMD) for latency hiding on the streaming read+convert chain.
// NOTE: no nontemporal hints anywhere — nt reads of producer-written buffers
// returned stale data (rounds 3-5, deterministic absmax 2.2).
// ---------------------------------------------------------------------------
__global__ __launch_bounds__(512) void prep_adj(const float* __restrict__ adj,
                                                float* __restrict__ dv,
                                                uint4* __restrict__ Af) {
  const int tid = threadIdx.x;
  const int m0 = blockIdx.x * 16;
  const int r = tid & 15;            // row within 16-row slice (lane&15)
  const int cg = tid >> 4;           // 0..31 col-group
  const float* src = adj + (long)(m0 + r) * 8192 + cg * 8;
  uint4* wbase = Af + (((long)(blockIdx.x >> 2) * 256) * 4 + (blockIdx.x & 3)) * 64 + (tid & 63);
  const int ksub = tid >> 6;         // wave id 0..7; ktile = p*8 + ksub

  float s = 0.f;
  #pragma unroll 4
  for (int p = 0; p < 32; ++p) {
    float4 a = *(const float4*)(src + p * 256);
    float4 b = *(const float4*)(src + p * 256 + 4);
    s += (a.x + a.y) + (a.z + a.w) + (b.x + b.y) + (b.z + b.w);
    uint4 o;
    o.x = pk2(a.x, a.y); o.y = pk2(a.z, a.w);
    o.z = pk2(b.x, b.y); o.w = pk2(b.z, b.w);
    wbase[(long)(p * 8 + ksub) * 256] = o;
  }
  // reduce 32 partials per row: lanes {r, r+16, r+32, r+48} in each of 8 waves
  s += __shfl_xor(s, 16);
  s += __shfl_xor(s, 32);
  __shared__ float red[8][16];
  if ((tid & 63) < 16) red[tid >> 6][r] = s;
  __syncthreads();
  if (tid < 16) {
    float t = ((red[0][tid] + red[1][tid]) + (red[2][tid] + red[3][tid])) +
              ((red[4][tid] + red[5][tid]) + (red[6][tid] + red[7][tid]));
    dv[m0 + tid] = rsqrtf(fmaxf(t, 1e-6f));
  }
}

// ---------------------------------------------------------------------------
// build_xt: blocks 0..127: X1Ts tile-major pre-swizzled: tile kt (64 k),
//   element offset kt*16384 + n*64 + (g^(n&7))*8 holds x-group g, d-scaled.
// Blocks 128..191: W1 f32->bf16.  Blocks 192..255: W2 f32->bf16.
// (cvt folded in to save two kernel launches; block-uniform branch.)
// ---------------------------------------------------------------------------
__global__ __launch_bounds__(256) void build_xt(const float* __restrict__ x,
                                                const float* __restrict__ dv,
                                                unsigned short* __restrict__ xt,
                                                const float* __restrict__ W1,
                                                unsigned short* __restrict__ W1b,
                                                const float* __restrict__ W2,
                                                unsigned short* __restrict__ W2b) {
  const int tid = threadIdx.x;
  if (blockIdx.x >= 128) {
    const int wi = blockIdx.x >= 192;
    const float* wsrc = wi ? W2 : W1;
    unsigned short* wdst = wi ? W2b : W1b;
    int i = (blockIdx.x - (wi ? 192 : 128)) * 256 + tid;
    float4 v = *(const float4*)(wsrc + i * 4);
    uint2 o;
    o.x = pk2(v.x, v.y); o.y = pk2(v.z, v.w);
    *(uint2*)(wdst + i * 4) = o;
    return;
  }
  __shared__ float t[64][257];
  const int k0 = blockIdx.x * 64;
  #pragma unroll
  for (int i = 0; i < 16; ++i) {
    int idx = i * 1024 + tid * 4;
    int r = idx >> 8, c = idx & 255;
    float4 v = *(const float4*)(x + (long)(k0 + r) * 256 + c);
    float dd = dv[k0 + r];
    t[r][c] = v.x * dd; t[r][c + 1] = v.y * dd;
    t[r][c + 2] = v.z * dd; t[r][c + 3] = v.w * dd;
  }
  __syncthreads();
  const int n = tid;
  unsigned short* dst = xt + (long)blockIdx.x * 16384 + n * 64;
  #pragma unroll
  for (int gg = 0; gg < 8; ++gg) {
    int q = gg ^ (n & 7);
    uint4 o;
    #pragma unroll
    for (int jj = 0; jj < 4; ++jj) {
      int k = gg * 8 + jj * 2;
      ((unsigned*)&o)[jj] = pk2(t[k][n], t[k + 1][n]);
    }
    *(uint4*)(dst + q * 8) = o;
  }
}

// ---------------------------------------------------------------------------
// gemm_big: Cp[by][m][n] = sum_{k chunk} Abf[m][k] * X[n][k]
// BM=128, BN=128, BK=64. 512 thr, 8 waves as 4M x 2N, wave tile 32x64.
// LDS 2x16KB -> __launch_bounds__(512,4) gives 2 blocks/CU: while one block
// sits in its vmcnt(0)+barrier drain the other issues MFMA (m114 overlap) —
// same mechanism r6 tried via splitk=8 but without the +32MB Cp cost.
// Grid x=128 encodes (bx,bn); XCD-pair swizzle puts both bn-halves of one bx
// on the SAME XCD so the A panel is HBM-fetched once, L2-hit the 2nd time.
// Sync is full-drain vmcnt(0)+__syncthreads (bulletproof; no counted vmcnt).
// Output partials f16 (proven r1/r6/r7).
// ---------------------------------------------------------------------------
#define BM 128
#define BN 128

__global__ __launch_bounds__(512, 4) void gemm_big(const uint4* __restrict__ Af,
                                                   const unsigned short* __restrict__ Bt,
                                                   unsigned short* __restrict__ Cp, int kchunk) {
  __shared__ __align__(16) unsigned short Bl[2][BN * 64];   // 2 x 16 KB
  const int tid = threadIdx.x, lane = tid & 63, w = tid >> 6;
  const int wm = w >> 1, wn = w & 1;          // 4M x 2N, wave tile 32x64
  const int d = blockIdx.x;
  const int v = (d & 7) * 16 + (d >> 3);      // bijective XCD-pair swizzle
  const long bx = v >> 1;
  const int bn = v & 1;
  const long by = blockIdx.y;
  const int kbase = (int)by * kchunk;
  const int NT = kchunk >> 6;                 // even (kchunk multiple of 128)

  const uint4* ap = Af + (((bx * 2 + (wm >> 1)) * 256 + (kbase >> 5)) * 4 + (wm & 1) * 2) * 64 + lane;
  const unsigned short* bsrc = Bt + (long)(kbase >> 6) * 16384 + bn * 8192 + w * 1024 + lane * 8;

  uint4 abA[4], abB[4];
  fx4 acc[2][4] = {};

  auto loadA = [&](int kt, uint4 (&dreg)[4]) {
    #pragma unroll
    for (int mf = 0; mf < 2; ++mf)
      #pragma unroll
      for (int kk = 0; kk < 2; ++kk)
        dreg[mf * 2 + kk] = ap[((long)kt * 8 + kk * 4 + mf) * 64];
  };
  auto stageB = [&](int kt, int buf) {
    #pragma unroll
    for (int i = 0; i < 2; ++i)
      __builtin_amdgcn_global_load_lds(
          (const unsigned int*)(bsrc + (long)kt * 16384 + i * 512),
          (unsigned int*)&Bl[buf][(w * 2 + i) * 512], 16, 0, 0);
  };
  auto compute = [&](uint4 (&ab)[4], int buf) {
    #pragma unroll
    for (int kk = 0; kk < 2; ++kk) {
      #pragma unroll
      for (int nf = 0; nf < 4; ++nf) {
        int n = wn * 64 + nf * 16 + (lane & 15);
        int k8 = kk * 4 + (lane >> 4);
        const s8v bf = *(const s8v*)&Bl[buf][n * 64 + ((k8 ^ (n & 7)) << 3)];
        #pragma unroll
        for (int mf = 0; mf < 2; ++mf)
          acc[mf][nf] = __builtin_amdgcn_mfma_f32_16x16x32_bf16(
              *(const s8v*)&ab[mf * 2 + kk], bf, acc[mf][nf], 0, 0, 0);
      }
    }
  };

  stageB(0, 0); loadA(0, abA);
  asm volatile("s_waitcnt vmcnt(0)" ::: "memory");
  __syncthreads();
  for (int kt = 0; kt < NT; kt += 2) {
    if (kt + 1 < NT) { stageB(kt + 1, 1); loadA(kt + 1, abB); }
    compute(abA, 0);
    asm volatile("s_waitcnt vmcnt(0)" ::: "memory");
    __syncthreads();
    if (kt + 2 < NT) { stageB(kt + 2, 0); loadA(kt + 2, abA); }
    if (kt + 1 < NT) {
      compute(abB, 1);
      asm volatile("s_waitcnt vmcnt(0)" ::: "memory");
      __syncthreads();
    }
  }

  unsigned short* outp = Cp + (by * 8192 + bx * BM) * 256;
  #pragma unroll
  for (int mf = 0; mf < 2; ++mf)
    #pragma unroll
    for (int nf = 0; nf < 4; ++nf)
      #pragma unroll
      for (int j = 0; j < 4; ++j) {
        int r = wm * 32 + mf * 16 + (lane >> 4) * 4 + j;
        int cc = bn * 128 + wn * 64 + nf * 16 + (lane & 15);
        outp[(long)r * 256 + cc] = f2h(acc[mf][nf][j]);
      }
}

// ---------------------------------------------------------------------------
// epi_kernel: splitK-reduce (f16 partials) + d-scale + (h @ W^T + b) + LN +
// GELU + out. 32-row tiles, 256 blocks, 256 threads (4 waves, wave tile 16x128).
// ---------------------------------------------------------------------------
template <int LAYER2>
__global__ __launch_bounds__(256) void epi_kernel(const unsigned short* __restrict__ Cp, int splitk,
                                                  const float* __restrict__ dv,
                                                  const unsigned short* __restrict__ Wb,
                                                  const float* __restrict__ bias,
                                                  const float* __restrict__ g,
                                                  const float* __restrict__ beta,
                                                  const float* __restrict__ xres,
                                                  unsigned short* __restrict__ xtOut,
                                                  float* __restrict__ out) {
  __shared__ __align__(16) unsigned short hA[32 * 256];
  __shared__ float Zl[32][257];
  __shared__ float redS[4][32], redSS[4][32];
  __shared__ float stats[32][2];
  const int tid = threadIdx.x, lane = tid & 63, w = tid >> 6;
  const int m0 = blockIdx.x * 32;

  // phase 1: split-K reduce (f16 partials) + d-scale -> bf16 LDS (swizzled)
  #pragma unroll
  for (int i = 0; i < 8; ++i) {
    int idx = i * 1024 + tid * 4;
    int r = idx >> 8, c = idx & 255;
    float sx = 0.f, sy = 0.f, sz = 0.f, sw = 0.f;
    for (int sk = 0; sk < splitk; ++sk) {
      uint2 v = *(const uint2*)(Cp + ((long)sk * 8192 + m0 + r) * 256 + c);
      h2v p0 = __builtin_bit_cast(h2v, v.x);
      h2v p1 = __builtin_bit_cast(h2v, v.y);
      sx += (float)p0.x; sy += (float)p0.y;
      sz += (float)p1.x; sw += (float)p1.y;
    }
    float dd = dv[m0 + r];
    uint2 o;
    o.x = pk2(sx * dd, sy * dd); o.y = pk2(sz * dd, sw * dd);
    *(uint2*)&hA[r * 256 + (c ^ ((r & 7) << 3))] = o;
  }
  __syncthreads();

  // phase 2: Z = h @ W^T (wave (wm,wn) = (w>>1, w&1), tile 16x128)
  fx4 acc[8] = {};
  const int row = (w >> 1) * 16 + (lane & 15);
  #pragma unroll
  for (int k0 = 0; k0 < 256; k0 += 32) {
    int kc = k0 + (lane >> 4) * 8;
    s8v a = *(const s8v*)&hA[row * 256 + (kc ^ ((row & 7) << 3))];
    #pragma unroll
    for (int nf = 0; nf < 8; ++nf) {
      int n = (w & 1) * 128 + nf * 16 + (lane & 15);
      s8v b = *(const s8v*)(Wb + (long)n * 256 + kc);
      acc[nf] = __builtin_amdgcn_mfma_f32_16x16x32_bf16(a, b, acc[nf], 0, 0, 0);
    }
  }

  // phase 3: + bias -> Zl
  #pragma unroll
  for (int nf = 0; nf < 8; ++nf)
    #pragma unroll
    for (int j = 0; j < 4; ++j) {
      int r = (w >> 1) * 16 + (lane >> 4) * 4 + j;
      int cc = (w & 1) * 128 + nf * 16 + (lane & 15);
      Zl[r][cc] = acc[nf][j] + bias[cc];
    }
  __syncthreads();

  // phase 4: LN stats (8 threads/row)
  {
    int r = tid & 31, q = tid >> 5;
    float s = 0.f, ss = 0.f;
    #pragma unroll
    for (int c = 0; c < 32; ++c) {
      float v = Zl[r][q * 32 + c];
      s += v; ss += v * v;
    }
    s += __shfl_xor(s, 32); ss += __shfl_xor(ss, 32);
    if (lane < 32) { redS[w][r] = s; redSS[w][r] = ss; }
  }
  __syncthreads();
  if (tid < 32) {
    float s = (redS[0][tid] + redS[1][tid]) + (redS[2][tid] + redS[3][tid]);
    float ss = (redSS[0][tid] + redSS[1][tid]) + (redSS[2][tid] + redSS[3][tid]);
    float mu = s * (1.f / 256.f);
    float var = ss * (1.f / 256.f) - mu * mu;
    stats[tid][0] = mu; stats[tid][1] = rsqrtf(var + LN_EPS);
  }
  __syncthreads();

  // phase 5: LN apply + GELU (+ next-layer d-scale)
  {
    int r = tid & 31, q = tid >> 5;
    float mu = stats[r][0], inv = stats[r][1];
    float dd = LAYER2 ? 1.f : dv[m0 + r];
    #pragma unroll
    for (int c = 0; c < 32; ++c) {
      int cc = q * 32 + c;
      float v = (Zl[r][cc] - mu) * inv * g[cc] + beta[cc];
      float ge = 0.5f * v * (1.f + erff(v * 0.70710678118f));
      Zl[r][cc] = ge * dd;
    }
  }
  __syncthreads();

  // phase 6: output
  if (!LAYER2) {
    // X2Ts tile-major pre-swizzled (same convention as build_xt)
    int n = tid;
    unsigned short* dst = xtOut + ((long)(m0 >> 6)) * 16384 + n * 64;
    int g0 = (m0 & 32) >> 3;   // 0 or 4
    #pragma unroll
    for (int gi = 0; gi < 4; ++gi) {
      int gg = g0 + gi;
      int q = gg ^ (n & 7);
      uint4 o;
      #pragma unroll
      for (int jj = 0; jj < 4; ++jj) {
        int rr = gi * 8 + jj * 2;
        ((unsigned*)&o)[jj] = pk2(Zl[rr][n], Zl[rr + 1][n]);
      }
      *(uint4*)(dst + q * 8) = o;
    }
  } else {
    int c = tid;
    #pragma unroll 8
    for (int r = 0; r < 32; ++r) {
      long idx = (long)(m0 + r) * 256 + c;
      out[idx] = Zl[r][c] + xres[idx];
    }
  }
}

// ---------------------------------------------------------------- launcher
extern "C" void kernel_launch(void* const* d_in, const int* in_sizes, int n_in,
                              void* d_out, int out_size, void* d_ws, size_t ws_size,
                              hipStream_t stream) {
  const float* x   = (const float*)d_in[0];
  const float* adj = (const float*)d_in[1];
  const float* W1  = (const float*)d_in[2];
  const float* b1  = (const float*)d_in[3];
  const float* g1  = (const float*)d_in[4];
  const float* be1 = (const float*)d_in[5];
  const float* W2  = (const float*)d_in[6];
  const float* b2  = (const float*)d_in[7];
  const float* g2  = (const float*)d_in[8];
  const float* be2 = (const float*)d_in[9];
  float* out = (float*)d_out;

  char* ws = (char*)d_ws;
  size_t off = 0;
  uint4* Af = (uint4*)(ws); off += 134217728;                       // 128 MB
  unsigned short* X1T = (unsigned short*)(ws + off); off += 4194304;
  unsigned short* X2T = (unsigned short*)(ws + off); off += 4194304;
  unsigned short* W1b = (unsigned short*)(ws + off); off += 131072;
  unsigned short* W2b = (unsigned short*)(ws + off); off += 131072;
  float* dvec = (float*)(ws + off); off += 32768;
  unsigned short* Cpart = (unsigned short*)(ws + off);

  int splitk = 4;
  while (splitk > 1 && off + (size_t)splitk * 8192 * 256 * 2 > ws_size) splitk >>= 1;
  int kchunk = 8192 / splitk;

  prep_adj<<<512, 512, 0, stream>>>(adj, dvec, Af);
  build_xt<<<256, 256, 0, stream>>>(x, dvec, X1T, W1, W1b, W2, W2b);

  gemm_big<<<dim3(128, splitk), 512, 0, stream>>>(Af, X1T, Cpart, kchunk);
  epi_kernel<0><<<256, 256, 0, stream>>>(Cpart, splitk, dvec, W1b, b1, g1, be1,
                                         nullptr, X2T, nullptr);
  gemm_big<<<dim3(128, splitk), 512, 0, stream>>>(Af, X2T, Cpart, kchunk);
  epi_kernel<1><<<256, 256, 0, stream>>>(Cpart, splitk, dvec, W2b, b2, g2, be2,
                                         x, nullptr, out);
}

// Round 9
// 224.228 us; speedup vs baseline: 1.2355x; 1.0154x over previous
//
#include <hip/hip_runtime.h>
#include <hip/hip_bf16.h>
#include <math.h>

#define LN_EPS 1e-5f

typedef __attribute__((ext_vector_type(4))) float fx4;
typedef __attribute__((ext_vector_type(8))) short s8v;   // 8 bf16 in 4 VGPRs
typedef __attribute__((ext_vector_type(2))) _Float16 h2v;

__device__ inline unsigned f2bf(float f) {
  unsigned u = __builtin_bit_cast(unsigned, f);
  return (u + 0x7fffu + ((u >> 16) & 1u)) >> 16;
}
__device__ inline unsigned pk2(float a, float b) {
  return f2bf(a) | (f2bf(b) << 16);
}
__device__ inline unsigned short f2h(float f) {
  return __builtin_bit_cast(unsigned short, (_Float16)f);
}

// ---------------------------------------------------------------------------
// prep_adj: one pass over adj f32. Produces:
//   dv[i]  = rsqrt(clip(rowsum(adj_i), 1e-6))
//   Af     = bf16(adj) in MFMA A-fragment layout:
//            uint4 index ((mb64*256 + ktile)*4 + mfq)*64 + lane
//            lane holds row mb64*64+mfq*16+(lane&15), k = ktile*32+(lane>>4)*8..+7
// Block = 16 rows (one mfq slice). 512 blocks x 512 threads (8 waves).
// adj loads are NONTEMPORAL (pure host-written input, read exactly once):
// keeps the 256 MB adj stream from evicting the 128 MB Af being written, so
// Af stays L3-resident and BOTH gemms read A at Infinity-Cache BW not HBM.
// (nt isolation: rounds 3-5's failure set included nt-load of producer-written
// Cp; this tests nt on a pure input only. Known failure signature: 2.203125.)
// ---------------------------------------------------------------------------
__global__ __launch_bounds__(512) void prep_adj(const float* __restrict__ adj,
                                                float* __restrict__ dv,
                                                uint4* __restrict__ Af) {
  const int tid = threadIdx.x;
  const int m0 = blockIdx.x * 16;
  const int r = tid & 15;            // row within 16-row slice (lane&15)
  const int cg = tid >> 4;           // 0..31 col-group
  const float* src = adj + (long)(m0 + r) * 8192 + cg * 8;
  uint4* wbase = Af + (((long)(blockIdx.x >> 2) * 256) * 4 + (blockIdx.x & 3)) * 64 + (tid & 63);
  const int ksub = tid >> 6;         // wave id 0..7; ktile = p*8 + ksub

  float s = 0.f;
  #pragma unroll 4
  for (int p = 0; p < 32; ++p) {
    fx4 a = __builtin_nontemporal_load((const fx4*)(src + p * 256));
    fx4 b = __builtin_nontemporal_load((const fx4*)(src + p * 256 + 4));
    s += (a.x + a.y) + (a.z + a.w) + (b.x + b.y) + (b.z + b.w);
    uint4 o;
    o.x = pk2(a.x, a.y); o.y = pk2(a.z, a.w);
    o.z = pk2(b.x, b.y); o.w = pk2(b.z, b.w);
    wbase[(long)(p * 8 + ksub) * 256] = o;
  }
  // reduce 32 partials per row: lanes {r, r+16, r+32, r+48} in each of 8 waves
  s += __shfl_xor(s, 16);
  s += __shfl_xor(s, 32);
  __shared__ float red[8][16];
  if ((tid & 63) < 16) red[tid >> 6][r] = s;
  __syncthreads();
  if (tid < 16) {
    float t = ((red[0][tid] + red[1][tid]) + (red[2][tid] + red[3][tid])) +
              ((red[4][tid] + red[5][tid]) + (red[6][tid] + red[7][tid]));
    dv[m0 + tid] = rsqrtf(fmaxf(t, 1e-6f));
  }
}

// ---------------------------------------------------------------------------
// build_xt: blocks 0..127: X1Ts tile-major pre-swizzled: tile kt (64 k),
//   element offset kt*16384 + n*64 + (g^(n&7))*8 holds x-group g, d-scaled.
// Blocks 128..191: W1 f32->bf16.  Blocks 192..255: W2 f32->bf16.
// ---------------------------------------------------------------------------
__global__ __launch_bounds__(256) void build_xt(const float* __restrict__ x,
                                                const float* __restrict__ dv,
                                                unsigned short* __restrict__ xt,
                                                const float* __restrict__ W1,
                                                unsigned short* __restrict__ W1b,
                                                const float* __restrict__ W2,
                                                unsigned short* __restrict__ W2b) {
  const int tid = threadIdx.x;
  if (blockIdx.x >= 128) {
    const int wi = blockIdx.x >= 192;
    const float* wsrc = wi ? W2 : W1;
    unsigned short* wdst = wi ? W2b : W1b;
    int i = (blockIdx.x - (wi ? 192 : 128)) * 256 + tid;
    float4 v = *(const float4*)(wsrc + i * 4);
    uint2 o;
    o.x = pk2(v.x, v.y); o.y = pk2(v.z, v.w);
    *(uint2*)(wdst + i * 4) = o;
    return;
  }
  __shared__ float t[64][257];
  const int k0 = blockIdx.x * 64;
  #pragma unroll
  for (int i = 0; i < 16; ++i) {
    int idx = i * 1024 + tid * 4;
    int r = idx >> 8, c = idx & 255;
    float4 v = *(const float4*)(x + (long)(k0 + r) * 256 + c);
    float dd = dv[k0 + r];
    t[r][c] = v.x * dd; t[r][c + 1] = v.y * dd;
    t[r][c + 2] = v.z * dd; t[r][c + 3] = v.w * dd;
  }
  __syncthreads();
  const int n = tid;
  unsigned short* dst = xt + (long)blockIdx.x * 16384 + n * 64;
  #pragma unroll
  for (int gg = 0; gg < 8; ++gg) {
    int q = gg ^ (n & 7);
    uint4 o;
    #pragma unroll
    for (int jj = 0; jj < 4; ++jj) {
      int k = gg * 8 + jj * 2;
      ((unsigned*)&o)[jj] = pk2(t[k][n], t[k + 1][n]);
    }
    *(uint4*)(dst + q * 8) = o;
  }
}

// ---------------------------------------------------------------------------
// gemm_big: Cp[by][m][n] = sum_{k chunk} Abf[m][k] * X[n][k]
// BM=128, BN=128, BK=64. 512 thr, 8 waves as 4M x 2N, wave tile 32x64.
// __launch_bounds__(512,4) + 32KB LDS -> 2 blocks/CU (barrier-drain overlap).
// XCD-pair swizzle co-locates both bn-halves of one bx (A L2-shared).
// Output partials f16.  (r8 structure — verified 227.7 µs.)
// ---------------------------------------------------------------------------
#define BM 128
#define BN 128

__global__ __launch_bounds__(512, 4) void gemm_big(const uint4* __restrict__ Af,
                                                   const unsigned short* __restrict__ Bt,
                                                   unsigned short* __restrict__ Cp, int kchunk) {
  __shared__ __align__(16) unsigned short Bl[2][BN * 64];   // 2 x 16 KB
  const int tid = threadIdx.x, lane = tid & 63, w = tid >> 6;
  const int wm = w >> 1, wn = w & 1;          // 4M x 2N, wave tile 32x64
  const int d = blockIdx.x;
  const int v = (d & 7) * 16 + (d >> 3);      // bijective XCD-pair swizzle
  const long bx = v >> 1;
  const int bn = v & 1;
  const long by = blockIdx.y;
  const int kbase = (int)by * kchunk;
  const int NT = kchunk >> 6;                 // even (kchunk multiple of 128)

  const uint4* ap = Af + (((bx * 2 + (wm >> 1)) * 256 + (kbase >> 5)) * 4 + (wm & 1) * 2) * 64 + lane;
  const unsigned short* bsrc = Bt + (long)(kbase >> 6) * 16384 + bn * 8192 + w * 1024 + lane * 8;

  uint4 abA[4], abB[4];
  fx4 acc[2][4] = {};

  auto loadA = [&](int kt, uint4 (&dreg)[4]) {
    #pragma unroll
    for (int mf = 0; mf < 2; ++mf)
      #pragma unroll
      for (int kk = 0; kk < 2; ++kk)
        dreg[mf * 2 + kk] = ap[((long)kt * 8 + kk * 4 + mf) * 64];
  };
  auto stageB = [&](int kt, int buf) {
    #pragma unroll
    for (int i = 0; i < 2; ++i)
      __builtin_amdgcn_global_load_lds(
          (const unsigned int*)(bsrc + (long)kt * 16384 + i * 512),
          (unsigned int*)&Bl[buf][(w * 2 + i) * 512], 16, 0, 0);
  };
  auto compute = [&](uint4 (&ab)[4], int buf) {
    #pragma unroll
    for (int kk = 0; kk < 2; ++kk) {
      #pragma unroll
      for (int nf = 0; nf < 4; ++nf) {
        int n = wn * 64 + nf * 16 + (lane & 15);
        int k8 = kk * 4 + (lane >> 4);
        const s8v bf = *(const s8v*)&Bl[buf][n * 64 + ((k8 ^ (n & 7)) << 3)];
        #pragma unroll
        for (int mf = 0; mf < 2; ++mf)
          acc[mf][nf] = __builtin_amdgcn_mfma_f32_16x16x32_bf16(
              *(const s8v*)&ab[mf * 2 + kk], bf, acc[mf][nf], 0, 0, 0);
      }
    }
  };

  stageB(0, 0); loadA(0, abA);
  asm volatile("s_waitcnt vmcnt(0)" ::: "memory");
  __syncthreads();
  for (int kt = 0; kt < NT; kt += 2) {
    if (kt + 1 < NT) { stageB(kt + 1, 1); loadA(kt + 1, abB); }
    compute(abA, 0);
    asm volatile("s_waitcnt vmcnt(0)" ::: "memory");
    __syncthreads();
    if (kt + 2 < NT) { stageB(kt + 2, 0); loadA(kt + 2, abA); }
    if (kt + 1 < NT) {
      compute(abB, 1);
      asm volatile("s_waitcnt vmcnt(0)" ::: "memory");
      __syncthreads();
    }
  }

  unsigned short* outp = Cp + (by * 8192 + bx * BM) * 256;
  #pragma unroll
  for (int mf = 0; mf < 2; ++mf)
    #pragma unroll
    for (int nf = 0; nf < 4; ++nf)
      #pragma unroll
      for (int j = 0; j < 4; ++j) {
        int r = wm * 32 + mf * 16 + (lane >> 4) * 4 + j;
        int cc = bn * 128 + wn * 64 + nf * 16 + (lane & 15);
        outp[(long)r * 256 + cc] = f2h(acc[mf][nf][j]);
      }
}

// ---------------------------------------------------------------------------
// epi_kernel: splitK-reduce (f16 partials) + d-scale + (h @ W^T + b) + LN +
// GELU + out. 32-row tiles, 256 blocks, 256 threads (4 waves, wave tile 16x128).
// ---------------------------------------------------------------------------
template <int LAYER2>
__global__ __launch_bounds__(256) void epi_kernel(const unsigned short* __restrict__ Cp, int splitk,
                                                  const float* __restrict__ dv,
                                                  const unsigned short* __restrict__ Wb,
                                                  const float* __restrict__ bias,
                                                  const float* __restrict__ g,
                                                  const float* __restrict__ beta,
                                                  const float* __restrict__ xres,
                                                  unsigned short* __restrict__ xtOut,
                                                  float* __restrict__ out) {
  __shared__ __align__(16) unsigned short hA[32 * 256];
  __shared__ float Zl[32][257];
  __shared__ float redS[4][32], redSS[4][32];
  __shared__ float stats[32][2];
  const int tid = threadIdx.x, lane = tid & 63, w = tid >> 6;
  const int m0 = blockIdx.x * 32;

  // phase 1: split-K reduce (f16 partials) + d-scale -> bf16 LDS (swizzled)
  #pragma unroll
  for (int i = 0; i < 8; ++i) {
    int idx = i * 1024 + tid * 4;
    int r = idx >> 8, c = idx & 255;
    float sx = 0.f, sy = 0.f, sz = 0.f, sw = 0.f;
    for (int sk = 0; sk < splitk; ++sk) {
      uint2 v = *(const uint2*)(Cp + ((long)sk * 8192 + m0 + r) * 256 + c);
      h2v p0 = __builtin_bit_cast(h2v, v.x);
      h2v p1 = __builtin_bit_cast(h2v, v.y);
      sx += (float)p0.x; sy += (float)p0.y;
      sz += (float)p1.x; sw += (float)p1.y;
    }
    float dd = dv[m0 + r];
    uint2 o;
    o.x = pk2(sx * dd, sy * dd); o.y = pk2(sz * dd, sw * dd);
    *(uint2*)&hA[r * 256 + (c ^ ((r & 7) << 3))] = o;
  }
  __syncthreads();

  // phase 2: Z = h @ W^T (wave (wm,wn) = (w>>1, w&1), tile 16x128)
  fx4 acc[8] = {};
  const int row = (w >> 1) * 16 + (lane & 15);
  #pragma unroll
  for (int k0 = 0; k0 < 256; k0 += 32) {
    int kc = k0 + (lane >> 4) * 8;
    s8v a = *(const s8v*)&hA[row * 256 + (kc ^ ((row & 7) << 3))];
    #pragma unroll
    for (int nf = 0; nf < 8; ++nf) {
      int n = (w & 1) * 128 + nf * 16 + (lane & 15);
      s8v b = *(const s8v*)(Wb + (long)n * 256 + kc);
      acc[nf] = __builtin_amdgcn_mfma_f32_16x16x32_bf16(a, b, acc[nf], 0, 0, 0);
    }
  }

  // phase 3: + bias -> Zl
  #pragma unroll
  for (int nf = 0; nf < 8; ++nf)
    #pragma unroll
    for (int j = 0; j < 4; ++j) {
      int r = (w >> 1) * 16 + (lane >> 4) * 4 + j;
      int cc = (w & 1) * 128 + nf * 16 + (lane & 15);
      Zl[r][cc] = acc[nf][j] + bias[cc];
    }
  __syncthreads();

  // phase 4: LN stats (8 threads/row)
  {
    int r = tid & 31, q = tid >> 5;
    float s = 0.f, ss = 0.f;
    #pragma unroll
    for (int c = 0; c < 32; ++c) {
      float v = Zl[r][q * 32 + c];
      s += v; ss += v * v;
    }
    s += __shfl_xor(s, 32); ss += __shfl_xor(ss, 32);
    if (lane < 32) { redS[w][r] = s; redSS[w][r] = ss; }
  }
  __syncthreads();
  if (tid < 32) {
    float s = (redS[0][tid] + redS[1][tid]) + (redS[2][tid] + redS[3][tid]);
    float ss = (redSS[0][tid] + redSS[1][tid]) + (redSS[2][tid] + redSS[3][tid]);
    float mu = s * (1.f / 256.f);
    float var = ss * (1.f / 256.f) - mu * mu;
    stats[tid][0] = mu; stats[tid][1] = rsqrtf(var + LN_EPS);
  }
  __syncthreads();

  // phase 5: LN apply + GELU (+ next-layer d-scale)
  {
    int r = tid & 31, q = tid >> 5;
    float mu = stats[r][0], inv = stats[r][1];
    float dd = LAYER2 ? 1.f : dv[m0 + r];
    #pragma unroll
    for (int c = 0; c < 32; ++c) {
      int cc = q * 32 + c;
      float v = (Zl[r][cc] - mu) * inv * g[cc] + beta[cc];
      float ge = 0.5f * v * (1.f + erff(v * 0.70710678118f));
      Zl[r][cc] = ge * dd;
    }
  }
  __syncthreads();

  // phase 6: output
  if (!LAYER2) {
    // X2Ts tile-major pre-swizzled (same convention as build_xt)
    int n = tid;
    unsigned short* dst = xtOut + ((long)(m0 >> 6)) * 16384 + n * 64;
    int g0 = (m0 & 32) >> 3;   // 0 or 4
    #pragma unroll
    for (int gi = 0; gi < 4; ++gi) {
      int gg = g0 + gi;
      int q = gg ^ (n & 7);
      uint4 o;
      #pragma unroll
      for (int jj = 0; jj < 4; ++jj) {
        int rr = gi * 8 + jj * 2;
        ((unsigned*)&o)[jj] = pk2(Zl[rr][n], Zl[rr + 1][n]);
      }
      *(uint4*)(dst + q * 8) = o;
    }
  } else {
    int c = tid;
    #pragma unroll 8
    for (int r = 0; r < 32; ++r) {
      long idx = (long)(m0 + r) * 256 + c;
      out[idx] = Zl[r][c] + xres[idx];
    }
  }
}

// ---------------------------------------------------------------- launcher
extern "C" void kernel_launch(void* const* d_in, const int* in_sizes, int n_in,
                              void* d_out, int out_size, void* d_ws, size_t ws_size,
                              hipStream_t stream) {
  const float* x   = (const float*)d_in[0];
  const float* adj = (const float*)d_in[1];
  const float* W1  = (const float*)d_in[2];
  const float* b1  = (const float*)d_in[3];
  const float* g1  = (const float*)d_in[4];
  const float* be1 = (const float*)d_in[5];
  const float* W2  = (const float*)d_in[6];
  const float* b2  = (const float*)d_in[7];
  const float* g2  = (const float*)d_in[8];
  const float* be2 = (const float*)d_in[9];
  float* out = (float*)d_out;

  char* ws = (char*)d_ws;
  size_t off = 0;
  uint4* Af = (uint4*)(ws); off += 134217728;                       // 128 MB
  unsigned short* X1T = (unsigned short*)(ws + off); off += 4194304;
  unsigned short* X2T = (unsigned short*)(ws + off); off += 4194304;
  unsigned short* W1b = (unsigned short*)(ws + off); off += 131072;
  unsigned short* W2b = (unsigned short*)(ws + off); off += 131072;
  float* dvec = (float*)(ws + off); off += 32768;
  unsigned short* Cpart = (unsigned short*)(ws + off);

  int splitk = 4;
  while (splitk > 1 && off + (size_t)splitk * 8192 * 256 * 2 > ws_size) splitk >>= 1;
  int kchunk = 8192 / splitk;

  prep_adj<<<512, 512, 0, stream>>>(adj, dvec, Af);
  build_xt<<<256, 256, 0, stream>>>(x, dvec, X1T, W1, W1b, W2, W2b);

  gemm_big<<<dim3(128, splitk), 512, 0, stream>>>(Af, X1T, Cpart, kchunk);
  epi_kernel<0><<<256, 256, 0, stream>>>(Cpart, splitk, dvec, W1b, b1, g1, be1,
                                         nullptr, X2T, nullptr);
  gemm_big<<<dim3(128, splitk), 512, 0, stream>>>(Af, X2T, Cpart, kchunk);
  epi_kernel<1><<<256, 256, 0, stream>>>(Cpart, splitk, dvec, W2b, b2, g2, be2,
                                         x, nullptr, out);
}

// Round 10
// 214.340 us; speedup vs baseline: 1.2925x; 1.0461x over previous
//
#include <hip/hip_runtime.h>
#include <hip/hip_bf16.h>
#include <math.h>

#define LN_EPS 1e-5f

typedef __attribute__((ext_vector_type(4))) float fx4;
typedef __attribute__((ext_vector_type(8))) short s8v;   // 8 bf16 in 4 VGPRs
typedef __attribute__((ext_vector_type(2))) _Float16 h2v;

__device__ inline unsigned f2bf(float f) {
  unsigned u = __builtin_bit_cast(unsigned, f);
  return (u + 0x7fffu + ((u >> 16) & 1u)) >> 16;
}
__device__ inline unsigned pk2(float a, float b) {
  return f2bf(a) | (f2bf(b) << 16);
}
__device__ inline unsigned short f2h(float f) {
  return __builtin_bit_cast(unsigned short, (_Float16)f);
}

// ---------------------------------------------------------------------------
// prep_adj: one pass over adj f32. Produces:
//   dv[i]  = rsqrt(clip(rowsum(adj_i), 1e-6))
//   Af     = bf16(adj) in MFMA A-fragment layout:
//            uint4 index ((mb64*256 + ktile)*4 + mfq)*64 + lane
// Block = 16 rows (one mfq slice). 512 blocks x 512 threads (8 waves).
// adj loads NONTEMPORAL (pure host-written input, read once) — proven safe r9.
// nt on producer-written buffers is BANNED (rounds 3-5, absmax 2.203125).
// ---------------------------------------------------------------------------
__global__ __launch_bounds__(512) void prep_adj(const float* __restrict__ adj,
                                                float* __restrict__ dv,
                                                uint4* __restrict__ Af) {
  const int tid = threadIdx.x;
  const int m0 = blockIdx.x * 16;
  const int r = tid & 15;            // row within 16-row slice (lane&15)
  const int cg = tid >> 4;           // 0..31 col-group
  const float* src = adj + (long)(m0 + r) * 8192 + cg * 8;
  uint4* wbase = Af + (((long)(blockIdx.x >> 2) * 256) * 4 + (blockIdx.x & 3)) * 64 + (tid & 63);
  const int ksub = tid >> 6;         // wave id 0..7; ktile = p*8 + ksub

  float s = 0.f;
  #pragma unroll 4
  for (int p = 0; p < 32; ++p) {
    fx4 a = __builtin_nontemporal_load((const fx4*)(src + p * 256));
    fx4 b = __builtin_nontemporal_load((const fx4*)(src + p * 256 + 4));
    s += (a.x + a.y) + (a.z + a.w) + (b.x + b.y) + (b.z + b.w);
    uint4 o;
    o.x = pk2(a.x, a.y); o.y = pk2(a.z, a.w);
    o.z = pk2(b.x, b.y); o.w = pk2(b.z, b.w);
    wbase[(long)(p * 8 + ksub) * 256] = o;
  }
  // reduce 32 partials per row: lanes {r, r+16, r+32, r+48} in each of 8 waves
  s += __shfl_xor(s, 16);
  s += __shfl_xor(s, 32);
  __shared__ float red[8][16];
  if ((tid & 63) < 16) red[tid >> 6][r] = s;
  __syncthreads();
  if (tid < 16) {
    float t = ((red[0][tid] + red[1][tid]) + (red[2][tid] + red[3][tid])) +
              ((red[4][tid] + red[5][tid]) + (red[6][tid] + red[7][tid]));
    dv[m0 + tid] = rsqrtf(fmaxf(t, 1e-6f));
  }
}

// ---------------------------------------------------------------------------
// build_xt: blocks 0..127: X1Ts tile-major pre-swizzled: tile kt (64 k),
//   element offset kt*16384 + n*64 + (g^(n&7))*8 holds x-group g, d-scaled.
// Blocks 128..191: W1 f32->bf16.  Blocks 192..255: W2 f32->bf16.
// ---------------------------------------------------------------------------
__global__ __launch_bounds__(256) void build_xt(const float* __restrict__ x,
                                                const float* __restrict__ dv,
                                                unsigned short* __restrict__ xt,
                                                const float* __restrict__ W1,
                                                unsigned short* __restrict__ W1b,
                                                const float* __restrict__ W2,
                                                unsigned short* __restrict__ W2b) {
  const int tid = threadIdx.x;
  if (blockIdx.x >= 128) {
    const int wi = blockIdx.x >= 192;
    const float* wsrc = wi ? W2 : W1;
    unsigned short* wdst = wi ? W2b : W1b;
    int i = (blockIdx.x - (wi ? 192 : 128)) * 256 + tid;
    float4 v = *(const float4*)(wsrc + i * 4);
    uint2 o;
    o.x = pk2(v.x, v.y); o.y = pk2(v.z, v.w);
    *(uint2*)(wdst + i * 4) = o;
    return;
  }
  __shared__ float t[64][257];
  const int k0 = blockIdx.x * 64;
  #pragma unroll
  for (int i = 0; i < 16; ++i) {
    int idx = i * 1024 + tid * 4;
    int r = idx >> 8, c = idx & 255;
    float4 v = *(const float4*)(x + (long)(k0 + r) * 256 + c);
    float dd = dv[k0 + r];
    t[r][c] = v.x * dd; t[r][c + 1] = v.y * dd;
    t[r][c + 2] = v.z * dd; t[r][c + 3] = v.w * dd;
  }
  __syncthreads();
  const int n = tid;
  unsigned short* dst = xt + (long)blockIdx.x * 16384 + n * 64;
  #pragma unroll
  for (int gg = 0; gg < 8; ++gg) {
    int q = gg ^ (n & 7);
    uint4 o;
    #pragma unroll
    for (int jj = 0; jj < 4; ++jj) {
      int k = gg * 8 + jj * 2;
      ((unsigned*)&o)[jj] = pk2(t[k][n], t[k + 1][n]);
    }
    *(uint4*)(dst + q * 8) = o;
  }
}

// ---------------------------------------------------------------------------
// gemm_big: Cp[by][m][n] = sum_{k chunk} Abf[m][k] * X[n][k]
// BM=128, BN=128, BK=64. 512 thr, 8 waves as 4M x 2N, wave tile 32x64.
// __launch_bounds__(512,4) + 32KB LDS -> 2 blocks/CU (barrier-drain overlap).
// XCD-pair swizzle co-locates both bn-halves of one bx (A L2-shared).
// Output partials f16.  (r8 structure — verified.)
// ---------------------------------------------------------------------------
#define BM 128
#define BN 128

__global__ __launch_bounds__(512, 4) void gemm_big(const uint4* __restrict__ Af,
                                                   const unsigned short* __restrict__ Bt,
                                                   unsigned short* __restrict__ Cp, int kchunk) {
  __shared__ __align__(16) unsigned short Bl[2][BN * 64];   // 2 x 16 KB
  const int tid = threadIdx.x, lane = tid & 63, w = tid >> 6;
  const int wm = w >> 1, wn = w & 1;          // 4M x 2N, wave tile 32x64
  const int d = blockIdx.x;
  const int v = (d & 7) * 16 + (d >> 3);      // bijective XCD-pair swizzle
  const long bx = v >> 1;
  const int bn = v & 1;
  const long by = blockIdx.y;
  const int kbase = (int)by * kchunk;
  const int NT = kchunk >> 6;                 // even (kchunk multiple of 128)

  const uint4* ap = Af + (((bx * 2 + (wm >> 1)) * 256 + (kbase >> 5)) * 4 + (wm & 1) * 2) * 64 + lane;
  const unsigned short* bsrc = Bt + (long)(kbase >> 6) * 16384 + bn * 8192 + w * 1024 + lane * 8;

  uint4 abA[4], abB[4];
  fx4 acc[2][4] = {};

  auto loadA = [&](int kt, uint4 (&dreg)[4]) {
    #pragma unroll
    for (int mf = 0; mf < 2; ++mf)
      #pragma unroll
      for (int kk = 0; kk < 2; ++kk)
        dreg[mf * 2 + kk] = ap[((long)kt * 8 + kk * 4 + mf) * 64];
  };
  auto stageB = [&](int kt, int buf) {
    #pragma unroll
    for (int i = 0; i < 2; ++i)
      __builtin_amdgcn_global_load_lds(
          (const unsigned int*)(bsrc + (long)kt * 16384 + i * 512),
          (unsigned int*)&Bl[buf][(w * 2 + i) * 512], 16, 0, 0);
  };
  auto compute = [&](uint4 (&ab)[4], int buf) {
    #pragma unroll
    for (int kk = 0; kk < 2; ++kk) {
      #pragma unroll
      for (int nf = 0; nf < 4; ++nf) {
        int n = wn * 64 + nf * 16 + (lane & 15);
        int k8 = kk * 4 + (lane >> 4);
        const s8v bf = *(const s8v*)&Bl[buf][n * 64 + ((k8 ^ (n & 7)) << 3)];
        #pragma unroll
        for (int mf = 0; mf < 2; ++mf)
          acc[mf][nf] = __builtin_amdgcn_mfma_f32_16x16x32_bf16(
              *(const s8v*)&ab[mf * 2 + kk], bf, acc[mf][nf], 0, 0, 0);
      }
    }
  };

  stageB(0, 0); loadA(0, abA);
  asm volatile("s_waitcnt vmcnt(0)" ::: "memory");
  __syncthreads();
  for (int kt = 0; kt < NT; kt += 2) {
    if (kt + 1 < NT) { stageB(kt + 1, 1); loadA(kt + 1, abB); }
    compute(abA, 0);
    asm volatile("s_waitcnt vmcnt(0)" ::: "memory");
    __syncthreads();
    if (kt + 2 < NT) { stageB(kt + 2, 0); loadA(kt + 2, abA); }
    if (kt + 1 < NT) {
      compute(abB, 1);
      asm volatile("s_waitcnt vmcnt(0)" ::: "memory");
      __syncthreads();
    }
  }

  unsigned short* outp = Cp + (by * 8192 + bx * BM) * 256;
  #pragma unroll
  for (int mf = 0; mf < 2; ++mf)
    #pragma unroll
    for (int nf = 0; nf < 4; ++nf)
      #pragma unroll
      for (int j = 0; j < 4; ++j) {
        int r = wm * 32 + mf * 16 + (lane >> 4) * 4 + j;
        int cc = bn * 128 + wn * 64 + nf * 16 + (lane & 15);
        outp[(long)r * 256 + cc] = f2h(acc[mf][nf][j]);
      }
}

// ---------------------------------------------------------------------------
// epi_kernel: splitK-reduce (f16 partials) + d-scale + (h @ W^T + b) + LN +
// GELU + out. 32-row tiles, 256 blocks, now 512 threads (8 waves = 2/SIMD;
// was 4 waves = 1/SIMD with every phase barrier fully exposed).
// Phase 2 waves: 2M x 4N, wave tile 16x64.
// ---------------------------------------------------------------------------
template <int LAYER2>
__global__ __launch_bounds__(512) void epi_kernel(const unsigned short* __restrict__ Cp, int splitk,
                                                  const float* __restrict__ dv,
                                                  const unsigned short* __restrict__ Wb,
                                                  const float* __restrict__ bias,
                                                  const float* __restrict__ g,
                                                  const float* __restrict__ beta,
                                                  const float* __restrict__ xres,
                                                  unsigned short* __restrict__ xtOut,
                                                  float* __restrict__ out) {
  __shared__ __align__(16) unsigned short hA[32 * 256];
  __shared__ float Zl[32][257];
  __shared__ float redS[8][32], redSS[8][32];
  __shared__ float stats[32][2];
  const int tid = threadIdx.x, lane = tid & 63, w = tid >> 6;
  const int m0 = blockIdx.x * 32;

  // phase 1: split-K reduce (f16 partials) + d-scale -> bf16 LDS (swizzled)
  #pragma unroll
  for (int i = 0; i < 4; ++i) {
    int idx = i * 2048 + tid * 4;
    int r = idx >> 8, c = idx & 255;
    float sx = 0.f, sy = 0.f, sz = 0.f, sw = 0.f;
    for (int sk = 0; sk < splitk; ++sk) {
      uint2 v = *(const uint2*)(Cp + ((long)sk * 8192 + m0 + r) * 256 + c);
      h2v p0 = __builtin_bit_cast(h2v, v.x);
      h2v p1 = __builtin_bit_cast(h2v, v.y);
      sx += (float)p0.x; sy += (float)p0.y;
      sz += (float)p1.x; sw += (float)p1.y;
    }
    float dd = dv[m0 + r];
    uint2 o;
    o.x = pk2(sx * dd, sy * dd); o.y = pk2(sz * dd, sw * dd);
    *(uint2*)&hA[r * 256 + (c ^ ((r & 7) << 3))] = o;
  }
  __syncthreads();

  // phase 2: Z = h @ W^T; waves (wm,wn) = (w>>2, w&3), wave tile 16x64
  fx4 acc[4] = {};
  const int row = (w >> 2) * 16 + (lane & 15);
  #pragma unroll
  for (int k0 = 0; k0 < 256; k0 += 32) {
    int kc = k0 + (lane >> 4) * 8;
    s8v a = *(const s8v*)&hA[row * 256 + (kc ^ ((row & 7) << 3))];
    #pragma unroll
    for (int nf = 0; nf < 4; ++nf) {
      int n = (w & 3) * 64 + nf * 16 + (lane & 15);
      s8v b = *(const s8v*)(Wb + (long)n * 256 + kc);
      acc[nf] = __builtin_amdgcn_mfma_f32_16x16x32_bf16(a, b, acc[nf], 0, 0, 0);
    }
  }

  // phase 3: + bias -> Zl
  #pragma unroll
  for (int nf = 0; nf < 4; ++nf)
    #pragma unroll
    for (int j = 0; j < 4; ++j) {
      int r = (w >> 2) * 16 + (lane >> 4) * 4 + j;
      int cc = (w & 3) * 64 + nf * 16 + (lane & 15);
      Zl[r][cc] = acc[nf][j] + bias[cc];
    }
  __syncthreads();

  // phase 4: LN stats (16 threads/row)
  {
    int r = tid & 31, q = tid >> 5;   // q = 0..15
    float s = 0.f, ss = 0.f;
    #pragma unroll
    for (int c = 0; c < 16; ++c) {
      float v = Zl[r][q * 16 + c];
      s += v; ss += v * v;
    }
    s += __shfl_xor(s, 32); ss += __shfl_xor(ss, 32);
    if (lane < 32) { redS[w][r] = s; redSS[w][r] = ss; }
  }
  __syncthreads();
  if (tid < 32) {
    float s = ((redS[0][tid] + redS[1][tid]) + (redS[2][tid] + redS[3][tid])) +
              ((redS[4][tid] + redS[5][tid]) + (redS[6][tid] + redS[7][tid]));
    float ss = ((redSS[0][tid] + redSS[1][tid]) + (redSS[2][tid] + redSS[3][tid])) +
               ((redSS[4][tid] + redSS[5][tid]) + (redSS[6][tid] + redSS[7][tid]));
    float mu = s * (1.f / 256.f);
    float var = ss * (1.f / 256.f) - mu * mu;
    stats[tid][0] = mu; stats[tid][1] = rsqrtf(var + LN_EPS);
  }
  __syncthreads();

  // phase 5: LN apply + GELU (+ next-layer d-scale)
  {
    int r = tid & 31, q = tid >> 5;
    float mu = stats[r][0], inv = stats[r][1];
    float dd = LAYER2 ? 1.f : dv[m0 + r];
    #pragma unroll
    for (int c = 0; c < 16; ++c) {
      int cc = q * 16 + c;
      float v = (Zl[r][cc] - mu) * inv * g[cc] + beta[cc];
      float ge = 0.5f * v * (1.f + erff(v * 0.70710678118f));
      Zl[r][cc] = ge * dd;
    }
  }
  __syncthreads();

  // phase 6: output
  if (!LAYER2) {
    // X2Ts tile-major pre-swizzled; gg range split across tid>>8
    int n = tid & 255, half = tid >> 8;   // half = 0,1
    unsigned short* dst = xtOut + ((long)(m0 >> 6)) * 16384 + n * 64;
    int g0 = ((m0 & 32) >> 3) + half * 2;
    #pragma unroll
    for (int gi = 0; gi < 2; ++gi) {
      int gg = g0 + gi;
      int q = gg ^ (n & 7);
      uint4 o;
      #pragma unroll
      for (int jj = 0; jj < 4; ++jj) {
        int rr = (half * 2 + gi) * 8 + jj * 2;
        ((unsigned*)&o)[jj] = pk2(Zl[rr][n], Zl[rr + 1][n]);
      }
      *(uint4*)(dst + q * 8) = o;
    }
  } else {
    int c = tid & 255, half = tid >> 8;
    #pragma unroll 8
    for (int r2 = 0; r2 < 16; ++r2) {
      int r = half * 16 + r2;
      long idx = (long)(m0 + r) * 256 + c;
      out[idx] = Zl[r][c] + xres[idx];
    }
  }
}

// ---------------------------------------------------------------- launcher
extern "C" void kernel_launch(void* const* d_in, const int* in_sizes, int n_in,
                              void* d_out, int out_size, void* d_ws, size_t ws_size,
                              hipStream_t stream) {
  const float* x   = (const float*)d_in[0];
  const float* adj = (const float*)d_in[1];
  const float* W1  = (const float*)d_in[2];
  const float* b1  = (const float*)d_in[3];
  const float* g1  = (const float*)d_in[4];
  const float* be1 = (const float*)d_in[5];
  const float* W2  = (const float*)d_in[6];
  const float* b2  = (const float*)d_in[7];
  const float* g2  = (const float*)d_in[8];
  const float* be2 = (const float*)d_in[9];
  float* out = (float*)d_out;

  char* ws = (char*)d_ws;
  size_t off = 0;
  uint4* Af = (uint4*)(ws); off += 134217728;                       // 128 MB
  unsigned short* X1T = (unsigned short*)(ws + off); off += 4194304;
  unsigned short* X2T = (unsigned short*)(ws + off); off += 4194304;
  unsigned short* W1b = (unsigned short*)(ws + off); off += 131072;
  unsigned short* W2b = (unsigned short*)(ws + off); off += 131072;
  float* dvec = (float*)(ws + off); off += 32768;
  unsigned short* Cpart = (unsigned short*)(ws + off);

  int splitk = 4;
  while (splitk > 1 && off + (size_t)splitk * 8192 * 256 * 2 > ws_size) splitk >>= 1;
  int kchunk = 8192 / splitk;

  prep_adj<<<512, 512, 0, stream>>>(adj, dvec, Af);
  build_xt<<<256, 256, 0, stream>>>(x, dvec, X1T, W1, W1b, W2, W2b);

  gemm_big<<<dim3(128, splitk), 512, 0, stream>>>(Af, X1T, Cpart, kchunk);
  epi_kernel<0><<<256, 512, 0, stream>>>(Cpart, splitk, dvec, W1b, b1, g1, be1,
                                         nullptr, X2T, nullptr);
  gemm_big<<<dim3(128, splitk), 512, 0, stream>>>(Af, X2T, Cpart, kchunk);
  epi_kernel<1><<<256, 512, 0, stream>>>(Cpart, splitk, dvec, W2b, b2, g2, be2,
                                         x, nullptr, out);
}

// Round 12
// 206.205 us; speedup vs baseline: 1.3435x; 1.0395x over previous
//
#include <hip/hip_runtime.h>
#include <hip/hip_bf16.h>
#include <math.h>

#define LN_EPS 1e-5f

typedef __attribute__((ext_vector_type(4))) float fx4;
typedef __attribute__((ext_vector_type(8))) short s8v;   // 8 bf16 in 4 VGPRs
typedef __attribute__((ext_vector_type(2))) _Float16 h2v;

__device__ inline unsigned f2bf(float f) {
  unsigned u = __builtin_bit_cast(unsigned, f);
  return (u + 0x7fffu + ((u >> 16) & 1u)) >> 16;
}
__device__ inline unsigned pk2(float a, float b) {
  return f2bf(a) | (f2bf(b) << 16);
}
__device__ inline unsigned short f2h(float f) {
  return __builtin_bit_cast(unsigned short, (_Float16)f);
}

// ---------------------------------------------------------------------------
// prep_adj: one pass over adj f32. Produces:
//   dv[i]  = rsqrt(clip(rowsum(adj_i), 1e-6))
//   Af     = bf16(adj) in MFMA A-fragment layout:
//            uint4 index ((mb64*256 + ktile)*4 + mfq)*64 + lane
// Block = 16 rows (one mfq slice). 512 blocks x 512 threads (8 waves).
// adj loads NONTEMPORAL (pure host-written input, read once) — proven safe r9.
// nt on producer-written buffers is BANNED (rounds 3-5, absmax 2.203125).
// Hand-rolled counted-vmcnt barrier contracts in gemm are RETIRED (r11: NaN).
// ---------------------------------------------------------------------------
__global__ __launch_bounds__(512) void prep_adj(const float* __restrict__ adj,
                                                float* __restrict__ dv,
                                                uint4* __restrict__ Af) {
  const int tid = threadIdx.x;
  const int m0 = blockIdx.x * 16;
  const int r = tid & 15;            // row within 16-row slice (lane&15)
  const int cg = tid >> 4;           // 0..31 col-group
  const float* src = adj + (long)(m0 + r) * 8192 + cg * 8;
  uint4* wbase = Af + (((long)(blockIdx.x >> 2) * 256) * 4 + (blockIdx.x & 3)) * 64 + (tid & 63);
  const int ksub = tid >> 6;         // wave id 0..7; ktile = p*8 + ksub

  float s = 0.f;
  #pragma unroll 4
  for (int p = 0; p < 32; ++p) {
    fx4 a = __builtin_nontemporal_load((const fx4*)(src + p * 256));
    fx4 b = __builtin_nontemporal_load((const fx4*)(src + p * 256 + 4));
    s += (a.x + a.y) + (a.z + a.w) + (b.x + b.y) + (b.z + b.w);
    uint4 o;
    o.x = pk2(a.x, a.y); o.y = pk2(a.z, a.w);
    o.z = pk2(b.x, b.y); o.w = pk2(b.z, b.w);
    wbase[(long)(p * 8 + ksub) * 256] = o;
  }
  // reduce 32 partials per row: lanes {r, r+16, r+32, r+48} in each of 8 waves
  s += __shfl_xor(s, 16);
  s += __shfl_xor(s, 32);
  __shared__ float red[8][16];
  if ((tid & 63) < 16) red[tid >> 6][r] = s;
  __syncthreads();
  if (tid < 16) {
    float t = ((red[0][tid] + red[1][tid]) + (red[2][tid] + red[3][tid])) +
              ((red[4][tid] + red[5][tid]) + (red[6][tid] + red[7][tid]));
    dv[m0 + tid] = rsqrtf(fmaxf(t, 1e-6f));
  }
}

// ---------------------------------------------------------------------------
// build_xt: blocks 0..127: X1Ts tile-major pre-swizzled: tile kt (64 k),
//   element offset kt*16384 + n*64 + (g^(n&7))*8 holds x-group g, d-scaled.
// Blocks 128..191: W1 f32->bf16.  Blocks 192..255: W2 f32->bf16.
// ---------------------------------------------------------------------------
__global__ __launch_bounds__(256) void build_xt(const float* __restrict__ x,
                                                const float* __restrict__ dv,
                                                unsigned short* __restrict__ xt,
                                                const float* __restrict__ W1,
                                                unsigned short* __restrict__ W1b,
                                                const float* __restrict__ W2,
                                                unsigned short* __restrict__ W2b) {
  const int tid = threadIdx.x;
  if (blockIdx.x >= 128) {
    const int wi = blockIdx.x >= 192;
    const float* wsrc = wi ? W2 : W1;
    unsigned short* wdst = wi ? W2b : W1b;
    int i = (blockIdx.x - (wi ? 192 : 128)) * 256 + tid;
    float4 v = *(const float4*)(wsrc + i * 4);
    uint2 o;
    o.x = pk2(v.x, v.y); o.y = pk2(v.z, v.w);
    *(uint2*)(wdst + i * 4) = o;
    return;
  }
  __shared__ float t[64][257];
  const int k0 = blockIdx.x * 64;
  #pragma unroll
  for (int i = 0; i < 16; ++i) {
    int idx = i * 1024 + tid * 4;
    int r = idx >> 8, c = idx & 255;
    float4 v = *(const float4*)(x + (long)(k0 + r) * 256 + c);
    float dd = dv[k0 + r];
    t[r][c] = v.x * dd; t[r][c + 1] = v.y * dd;
    t[r][c + 2] = v.z * dd; t[r][c + 3] = v.w * dd;
  }
  __syncthreads();
  const int n = tid;
  unsigned short* dst = xt + (long)blockIdx.x * 16384 + n * 64;
  #pragma unroll
  for (int gg = 0; gg < 8; ++gg) {
    int q = gg ^ (n & 7);
    uint4 o;
    #pragma unroll
    for (int jj = 0; jj < 4; ++jj) {
      int k = gg * 8 + jj * 2;
      ((unsigned*)&o)[jj] = pk2(t[k][n], t[k + 1][n]);
    }
    *(uint4*)(dst + q * 8) = o;
  }
}

// ---------------------------------------------------------------------------
// gemm_big: Cp[by][m][n] = sum_{k chunk} Abf[m][k] * X[n][k]
// BM=128, BN=128, BK=64. 512 thr, 8 waves as 4M x 2N, wave tile 32x64.
// __launch_bounds__(512,4) + 32KB LDS -> 2 blocks/CU (barrier-drain overlap).
// XCD-pair swizzle co-locates both bn-halves of one bx (A L2-shared).
// Sync: full-drain vmcnt(0) + __syncthreads — r8/r10-proven. Counted-vmcnt
// raw-barrier contracts NaN'd twice (r11); retired for this session.
// Output partials f16.
// ---------------------------------------------------------------------------
#define BM 128
#define BN 128

__global__ __launch_bounds__(512, 4) void gemm_big(const uint4* __restrict__ Af,
                                                   const unsigned short* __restrict__ Bt,
                                                   unsigned short* __restrict__ Cp, int kchunk) {
  __shared__ __align__(16) unsigned short Bl[2][BN * 64];   // 2 x 16 KB
  const int tid = threadIdx.x, lane = tid & 63, w = tid >> 6;
  const int wm = w >> 1, wn = w & 1;          // 4M x 2N, wave tile 32x64
  const int d = blockIdx.x;
  const int v = (d & 7) * 16 + (d >> 3);      // bijective XCD-pair swizzle
  const long bx = v >> 1;
  const int bn = v & 1;
  const long by = blockIdx.y;
  const int kbase = (int)by * kchunk;
  const int NT = kchunk >> 6;                 // even (kchunk multiple of 128)

  const uint4* ap = Af + (((bx * 2 + (wm >> 1)) * 256 + (kbase >> 5)) * 4 + (wm & 1) * 2) * 64 + lane;
  const unsigned short* bsrc = Bt + (long)(kbase >> 6) * 16384 + bn * 8192 + w * 1024 + lane * 8;

  uint4 abA[4], abB[4];
  fx4 acc[2][4] = {};

  auto loadA = [&](int kt, uint4 (&dreg)[4]) {
    #pragma unroll
    for (int mf = 0; mf < 2; ++mf)
      #pragma unroll
      for (int kk = 0; kk < 2; ++kk)
        dreg[mf * 2 + kk] = ap[((long)kt * 8 + kk * 4 + mf) * 64];
  };
  auto stageB = [&](int kt, int buf) {
    #pragma unroll
    for (int i = 0; i < 2; ++i)
      __builtin_amdgcn_global_load_lds(
          (const unsigned int*)(bsrc + (long)kt * 16384 + i * 512),
          (unsigned int*)&Bl[buf][(w * 2 + i) * 512], 16, 0, 0);
  };
  auto compute = [&](uint4 (&ab)[4], int buf) {
    #pragma unroll
    for (int kk = 0; kk < 2; ++kk) {
      #pragma unroll
      for (int nf = 0; nf < 4; ++nf) {
        int n = wn * 64 + nf * 16 + (lane & 15);
        int k8 = kk * 4 + (lane >> 4);
        const s8v bf = *(const s8v*)&Bl[buf][n * 64 + ((k8 ^ (n & 7)) << 3)];
        #pragma unroll
        for (int mf = 0; mf < 2; ++mf)
          acc[mf][nf] = __builtin_amdgcn_mfma_f32_16x16x32_bf16(
              *(const s8v*)&ab[mf * 2 + kk], bf, acc[mf][nf], 0, 0, 0);
      }
    }
  };

  stageB(0, 0); loadA(0, abA);
  asm volatile("s_waitcnt vmcnt(0)" ::: "memory");
  __syncthreads();
  for (int kt = 0; kt < NT; kt += 2) {
    if (kt + 1 < NT) { stageB(kt + 1, 1); loadA(kt + 1, abB); }
    compute(abA, 0);
    asm volatile("s_waitcnt vmcnt(0)" ::: "memory");
    __syncthreads();
    if (kt + 2 < NT) { stageB(kt + 2, 0); loadA(kt + 2, abA); }
    if (kt + 1 < NT) {
      compute(abB, 1);
      asm volatile("s_waitcnt vmcnt(0)" ::: "memory");
      __syncthreads();
    }
  }

  unsigned short* outp = Cp + (by * 8192 + bx * BM) * 256;
  #pragma unroll
  for (int mf = 0; mf < 2; ++mf)
    #pragma unroll
    for (int nf = 0; nf < 4; ++nf)
      #pragma unroll
      for (int j = 0; j < 4; ++j) {
        int r = wm * 32 + mf * 16 + (lane >> 4) * 4 + j;
        int cc = bn * 128 + wn * 64 + nf * 16 + (lane & 15);
        outp[(long)r * 256 + cc] = f2h(acc[mf][nf][j]);
      }
}

// ---------------------------------------------------------------------------
// epi_kernel: splitK-reduce (f16 partials, COMPILE-TIME SK so the split-K
// loads unroll into independent requests instead of a serialized
// load->wait->add chain) + d-scale + (h @ W^T + b) + LN + GELU + out.
// 32-row tiles, 256 blocks, 512 threads (8 waves; phase2 waves 2M x 4N).
// ---------------------------------------------------------------------------
template <int LAYER2, int SK>
__global__ __launch_bounds__(512) void epi_kernel(const unsigned short* __restrict__ Cp,
                                                  const float* __restrict__ dv,
                                                  const unsigned short* __restrict__ Wb,
                                                  const float* __restrict__ bias,
                                                  const float* __restrict__ g,
                                                  const float* __restrict__ beta,
                                                  const float* __restrict__ xres,
                                                  unsigned short* __restrict__ xtOut,
                                                  float* __restrict__ out) {
  __shared__ __align__(16) unsigned short hA[32 * 256];
  __shared__ float Zl[32][257];
  __shared__ float redS[8][32], redSS[8][32];
  __shared__ float stats[32][2];
  const int tid = threadIdx.x, lane = tid & 63, w = tid >> 6;
  const int m0 = blockIdx.x * 32;

  // phase 1: split-K reduce (f16 partials) + d-scale -> bf16 LDS (swizzled)
  #pragma unroll
  for (int i = 0; i < 4; ++i) {
    int idx = i * 2048 + tid * 4;
    int r = idx >> 8, c = idx & 255;
    float sx = 0.f, sy = 0.f, sz = 0.f, sw = 0.f;
    #pragma unroll
    for (int sk = 0; sk < SK; ++sk) {
      uint2 v = *(const uint2*)(Cp + ((long)sk * 8192 + m0 + r) * 256 + c);
      h2v p0 = __builtin_bit_cast(h2v, v.x);
      h2v p1 = __builtin_bit_cast(h2v, v.y);
      sx += (float)p0.x; sy += (float)p0.y;
      sz += (float)p1.x; sw += (float)p1.y;
    }
    float dd = dv[m0 + r];
    uint2 o;
    o.x = pk2(sx * dd, sy * dd); o.y = pk2(sz * dd, sw * dd);
    *(uint2*)&hA[r * 256 + (c ^ ((r & 7) << 3))] = o;
  }
  __syncthreads();

  // phase 2: Z = h @ W^T; waves (wm,wn) = (w>>2, w&3), wave tile 16x64
  fx4 acc[4] = {};
  const int row = (w >> 2) * 16 + (lane & 15);
  #pragma unroll
  for (int k0 = 0; k0 < 256; k0 += 32) {
    int kc = k0 + (lane >> 4) * 8;
    s8v a = *(const s8v*)&hA[row * 256 + (kc ^ ((row & 7) << 3))];
    #pragma unroll
    for (int nf = 0; nf < 4; ++nf) {
      int n = (w & 3) * 64 + nf * 16 + (lane & 15);
      s8v b = *(const s8v*)(Wb + (long)n * 256 + kc);
      acc[nf] = __builtin_amdgcn_mfma_f32_16x16x32_bf16(a, b, acc[nf], 0, 0, 0);
    }
  }

  // phase 3: + bias -> Zl
  #pragma unroll
  for (int nf = 0; nf < 4; ++nf)
    #pragma unroll
    for (int j = 0; j < 4; ++j) {
      int r = (w >> 2) * 16 + (lane >> 4) * 4 + j;
      int cc = (w & 3) * 64 + nf * 16 + (lane & 15);
      Zl[r][cc] = acc[nf][j] + bias[cc];
    }
  __syncthreads();

  // phase 4: LN stats (16 threads/row)
  {
    int r = tid & 31, q = tid >> 5;   // q = 0..15
    float s = 0.f, ss = 0.f;
    #pragma unroll
    for (int c = 0; c < 16; ++c) {
      float v = Zl[r][q * 16 + c];
      s += v; ss += v * v;
    }
    s += __shfl_xor(s, 32); ss += __shfl_xor(ss, 32);
    if (lane < 32) { redS[w][r] = s; redSS[w][r] = ss; }
  }
  __syncthreads();
  if (tid < 32) {
    float s = ((redS[0][tid] + redS[1][tid]) + (redS[2][tid] + redS[3][tid])) +
              ((redS[4][tid] + redS[5][tid]) + (redS[6][tid] + redS[7][tid]));
    float ss = ((redSS[0][tid] + redSS[1][tid]) + (redSS[2][tid] + redSS[3][tid])) +
               ((redSS[4][tid] + redSS[5][tid]) + (redSS[6][tid] + redSS[7][tid]));
    float mu = s * (1.f / 256.f);
    float var = ss * (1.f / 256.f) - mu * mu;
    stats[tid][0] = mu; stats[tid][1] = rsqrtf(var + LN_EPS);
  }
  __syncthreads();

  // phase 5: LN apply + GELU (+ next-layer d-scale)
  {
    int r = tid & 31, q = tid >> 5;
    float mu = stats[r][0], inv = stats[r][1];
    float dd = LAYER2 ? 1.f : dv[m0 + r];
    #pragma unroll
    for (int c = 0; c < 16; ++c) {
      int cc = q * 16 + c;
      float v = (Zl[r][cc] - mu) * inv * g[cc] + beta[cc];
      float ge = 0.5f * v * (1.f + erff(v * 0.70710678118f));
      Zl[r][cc] = ge * dd;
    }
  }
  __syncthreads();

  // phase 6: output
  if (!LAYER2) {
    // X2Ts tile-major pre-swizzled; gg range split across tid>>8
    int n = tid & 255, half = tid >> 8;   // half = 0,1
    unsigned short* dst = xtOut + ((long)(m0 >> 6)) * 16384 + n * 64;
    int g0 = ((m0 & 32) >> 3) + half * 2;
    #pragma unroll
    for (int gi = 0; gi < 2; ++gi) {
      int gg = g0 + gi;
      int q = gg ^ (n & 7);
      uint4 o;
      #pragma unroll
      for (int jj = 0; jj < 4; ++jj) {
        int rr = (half * 2 + gi) * 8 + jj * 2;
        ((unsigned*)&o)[jj] = pk2(Zl[rr][n], Zl[rr + 1][n]);
      }
      *(uint4*)(dst + q * 8) = o;
    }
  } else {
    int c = tid & 255, half = tid >> 8;
    #pragma unroll 8
    for (int r2 = 0; r2 < 16; ++r2) {
      int r = half * 16 + r2;
      long idx = (long)(m0 + r) * 256 + c;
      out[idx] = Zl[r][c] + xres[idx];
    }
  }
}

// ---------------------------------------------------------------- launcher
extern "C" void kernel_launch(void* const* d_in, const int* in_sizes, int n_in,
                              void* d_out, int out_size, void* d_ws, size_t ws_size,
                              hipStream_t stream) {
  const float* x   = (const float*)d_in[0];
  const float* adj = (const float*)d_in[1];
  const float* W1  = (const float*)d_in[2];
  const float* b1  = (const float*)d_in[3];
  const float* g1  = (const float*)d_in[4];
  const float* be1 = (const float*)d_in[5];
  const float* W2  = (const float*)d_in[6];
  const float* b2  = (const float*)d_in[7];
  const float* g2  = (const float*)d_in[8];
  const float* be2 = (const float*)d_in[9];
  float* out = (float*)d_out;

  char* ws = (char*)d_ws;
  size_t off = 0;
  uint4* Af = (uint4*)(ws); off += 134217728;                       // 128 MB
  unsigned short* X1T = (unsigned short*)(ws + off); off += 4194304;
  unsigned short* X2T = (unsigned short*)(ws + off); off += 4194304;
  unsigned short* W1b = (unsigned short*)(ws + off); off += 131072;
  unsigned short* W2b = (unsigned short*)(ws + off); off += 131072;
  float* dvec = (float*)(ws + off); off += 32768;
  unsigned short* Cpart = (unsigned short*)(ws + off);

  int splitk = 4;
  while (splitk > 1 && off + (size_t)splitk * 8192 * 256 * 2 > ws_size) splitk >>= 1;
  int kchunk = 8192 / splitk;

  prep_adj<<<512, 512, 0, stream>>>(adj, dvec, Af);
  build_xt<<<256, 256, 0, stream>>>(x, dvec, X1T, W1, W1b, W2, W2b);

  gemm_big<<<dim3(128, splitk), 512, 0, stream>>>(Af, X1T, Cpart, kchunk);
  if (splitk == 4)
    epi_kernel<0, 4><<<256, 512, 0, stream>>>(Cpart, dvec, W1b, b1, g1, be1, nullptr, X2T, nullptr);
  else if (splitk == 2)
    epi_kernel<0, 2><<<256, 512, 0, stream>>>(Cpart, dvec, W1b, b1, g1, be1, nullptr, X2T, nullptr);
  else
    epi_kernel<0, 1><<<256, 512, 0, stream>>>(Cpart, dvec, W1b, b1, g1, be1, nullptr, X2T, nullptr);

  gemm_big<<<dim3(128, splitk), 512, 0, stream>>>(Af, X2T, Cpart, kchunk);
  if (splitk == 4)
    epi_kernel<1, 4><<<256, 512, 0, stream>>>(Cpart, dvec, W2b, b2, g2, be2, x, nullptr, out);
  else if (splitk == 2)
    epi_kernel<1, 2><<<256, 512, 0, stream>>>(Cpart, dvec, W2b, b2, g2, be2, x, nullptr, out);
  else
    epi_kernel<1, 1><<<256, 512, 0, stream>>>(Cpart, dvec, W2b, b2, g2, be2, x, nullptr, out);
}